// Round 1
// baseline (6249.427 us; speedup 1.0000x reference)
//
#include <hip/hip_runtime.h>

#define BN_EPS 1e-5f

// ---------------- degree / norm precompute ----------------

__global__ void k_deg_init(float* __restrict__ deg, int n) {
    int i = blockIdx.x * blockDim.x + threadIdx.x;
    if (i < n) deg[i] = 1.0f;   // self-loop
}

__global__ void k_deg_edges(const int* __restrict__ dst, float* __restrict__ deg, int e) {
    int i = blockIdx.x * blockDim.x + threadIdx.x;
    if (i < e) atomicAdd(&deg[dst[i]], 1.0f);
}

__global__ void k_deg_finalize(const float* __restrict__ deg, float* __restrict__ dis,
                               float* __restrict__ dinv, int n) {
    int i = blockIdx.x * blockDim.x + threadIdx.x;
    if (i < n) {
        float d = deg[i];
        dis[i]  = rsqrtf(d);
        dinv[i] = 1.0f / d;
    }
}

__global__ void k_edge_norm(const int* __restrict__ src, const int* __restrict__ dst,
                            const float* __restrict__ dis, float* __restrict__ norm, int e) {
    int i = blockIdx.x * blockDim.x + threadIdx.x;
    if (i < e) norm[i] = dis[src[i]] * dis[dst[i]];
}

// ---------------- dense GEMM: H = X @ W  (W staged in LDS) ----------------

template <int FIN, int FOUT>
__global__ void k_gemm(const float* __restrict__ X, const float* __restrict__ W,
                       float* __restrict__ H, int n_nodes) {
    __shared__ float Ws[FIN * FOUT];
    for (int i = threadIdx.x; i < FIN * FOUT; i += blockDim.x) Ws[i] = W[i];
    __syncthreads();
    constexpr int NPB = 256 / FOUT;   // nodes per block
    int node = blockIdx.x * NPB + threadIdx.x / FOUT;
    int f    = threadIdx.x % FOUT;
    if (node >= n_nodes) return;
    const float* xr = X + (size_t)node * FIN;
    float acc = 0.0f;
#pragma unroll
    for (int k = 0; k < FIN; ++k) acc += xr[k] * Ws[k * FOUT + f];
    H[(size_t)node * FOUT + f] = acc;
}

// ---------------- edge scatter: agg[dst] += h[src] * norm_e ----------------

template <int LG>  // LG = log2(F/4)
__global__ void k_scatter(const float* __restrict__ H, const int* __restrict__ src,
                          const int* __restrict__ dst, const float* __restrict__ norm,
                          float* __restrict__ agg, int nE) {
    constexpr int F = 4 << LG;
    long long tid = (long long)blockIdx.x * blockDim.x + threadIdx.x;
    long long total = (long long)nE << LG;
    if (tid >= total) return;
    int e = (int)(tid >> LG);
    int c = (int)(tid & ((1 << LG) - 1));
    int s = src[e], d = dst[e];
    const float4 hv = *(const float4*)(H + (size_t)s * F + c * 4);
    float ne = norm[e];
    float* ap = agg + (size_t)d * F + c * 4;
    atomicAdd(ap + 0, hv.x * ne);
    atomicAdd(ap + 1, hv.y * ne);
    atomicAdd(ap + 2, hv.z * ne);
    atomicAdd(ap + 3, hv.w * ne);
}

// ---------------- epilogue: self-loop + bias (+ BN) + ReLU ----------------

template <int F, bool HAS_BN>
__global__ void k_epilogue(const float* __restrict__ agg, const float* __restrict__ H,
                           const float* __restrict__ dinv, const float* __restrict__ b,
                           const float* __restrict__ g, const float* __restrict__ be,
                           const float* __restrict__ m, const float* __restrict__ v,
                           float* __restrict__ out, int n_nodes) {
    int t = blockIdx.x * blockDim.x + threadIdx.x;
    if (t >= n_nodes * F) return;
    int node = t / F;
    int f    = t % F;
    float val = agg[t] + H[t] * dinv[node] + b[f];
    if (HAS_BN) {
        float s = g[f] * rsqrtf(v[f] + BN_EPS);
        val = (val - m[f]) * s + be[f];
    }
    out[t] = fmaxf(val, 0.0f);
}

// ---------------- global mean pool ----------------

__global__ void k_pool(const float* __restrict__ H, const int* __restrict__ batch,
                       float* __restrict__ sums, float* __restrict__ cnt, int n_nodes) {
    int t = blockIdx.x * blockDim.x + threadIdx.x;
    if (t >= n_nodes * 128) return;
    int node = t >> 7;
    int f    = t & 127;
    int bb = batch[node];
    atomicAdd(&sums[bb * 128 + f], H[t]);
    if (f == 0) atomicAdd(&cnt[bb], 1.0f);
}

__global__ void k_pool_div(const float* __restrict__ sums, const float* __restrict__ cnt,
                           float* __restrict__ out, int nB) {
    int i = blockIdx.x * blockDim.x + threadIdx.x;
    if (i < nB * 128) out[i] = sums[i] / fmaxf(cnt[i >> 7], 1.0f);
}

// ---------------- launch ----------------

extern "C" void kernel_launch(void* const* d_in, const int* in_sizes, int n_in,
                              void* d_out, int out_size, void* d_ws, size_t ws_size,
                              hipStream_t stream) {
    const float* x   = (const float*)d_in[0];
    const int*   ei  = (const int*)d_in[1];
    const int*   bat = (const int*)d_in[2];
    const float* W1  = (const float*)d_in[3];
    const float* b1  = (const float*)d_in[4];
    const float* W2  = (const float*)d_in[5];
    const float* b2  = (const float*)d_in[6];
    const float* W3  = (const float*)d_in[7];
    const float* b3  = (const float*)d_in[8];
    const float* g1  = (const float*)d_in[9];
    const float* be1 = (const float*)d_in[10];
    const float* m1  = (const float*)d_in[11];
    const float* v1  = (const float*)d_in[12];
    const float* g2  = (const float*)d_in[13];
    const float* be2 = (const float*)d_in[14];
    const float* m2  = (const float*)d_in[15];
    const float* v2  = (const float*)d_in[16];

    const int N = in_sizes[0] / 22;
    const int E = in_sizes[1] / 2;
    const int B = out_size / 128;
    const int* src = ei;
    const int* dst = ei + E;

    float* ws   = (float*)d_ws;
    float* deg  = ws;                        // N
    float* dis  = deg  + N;                  // N
    float* dinv = dis  + N;                  // N
    float* norm = dinv + N;                  // E
    float* bufA = norm + E;                  // N*128
    float* bufB = bufA + (size_t)N * 128;    // N*128
    float* sums = bufB + (size_t)N * 128;    // B*128
    float* cnt  = sums + (size_t)B * 128;    // B

    const int T = 256;
    auto blk = [](long long n, int t) { return (int)((n + t - 1) / t); };

    // degree + norms
    k_deg_init<<<blk(N, T), T, 0, stream>>>(deg, N);
    k_deg_edges<<<blk(E, T), T, 0, stream>>>(dst, deg, E);
    k_deg_finalize<<<blk(N, T), T, 0, stream>>>(deg, dis, dinv, N);
    k_edge_norm<<<blk(E, T), T, 0, stream>>>(src, dst, dis, norm, E);

    // ---- layer 1: 22 -> 64, BN1, ReLU ----
    k_gemm<22, 64><<<blk(N, 4), T, 0, stream>>>(x, W1, bufA, N);
    hipMemsetAsync(bufB, 0, (size_t)N * 64 * sizeof(float), stream);
    k_scatter<4><<<blk((long long)E * 16, T), T, 0, stream>>>(bufA, src, dst, norm, bufB, E);
    k_epilogue<64, true><<<blk((long long)N * 64, T), T, 0, stream>>>(
        bufB, bufA, dinv, b1, g1, be1, m1, v1, bufB, N);

    // ---- layer 2: 64 -> 64, BN2, ReLU ----
    k_gemm<64, 64><<<blk(N, 4), T, 0, stream>>>(bufB, W2, bufA, N);
    hipMemsetAsync(bufB, 0, (size_t)N * 64 * sizeof(float), stream);
    k_scatter<4><<<blk((long long)E * 16, T), T, 0, stream>>>(bufA, src, dst, norm, bufB, E);
    k_epilogue<64, true><<<blk((long long)N * 64, T), T, 0, stream>>>(
        bufB, bufA, dinv, b2, g2, be2, m2, v2, bufB, N);

    // ---- layer 3: 64 -> 128, ReLU ----
    k_gemm<64, 128><<<blk(N, 2), T, 0, stream>>>(bufB, W3, bufA, N);
    hipMemsetAsync(bufB, 0, (size_t)N * 128 * sizeof(float), stream);
    k_scatter<5><<<blk((long long)E * 32, T), T, 0, stream>>>(bufA, src, dst, norm, bufB, E);
    k_epilogue<128, false><<<blk((long long)N * 128, T), T, 0, stream>>>(
        bufB, bufA, dinv, b3, nullptr, nullptr, nullptr, nullptr, bufB, N);

    // ---- global mean pool ----
    hipMemsetAsync(sums, 0, (size_t)(B * 128 + B) * sizeof(float), stream);
    k_pool<<<blk((long long)N * 128, T), T, 0, stream>>>(bufB, bat, sums, cnt, N);
    k_pool_div<<<blk(B * 128, T), T, 0, stream>>>(sums, cnt, (float*)d_out, B);
}

// Round 2
// 1206.776 us; speedup vs baseline: 5.1786x; 5.1786x over previous
//
#include <hip/hip_runtime.h>

#define BN_EPS 1e-5f

// ================= degree histogram / norms =================

__global__ void k_hist(const int* __restrict__ dst, int* __restrict__ deg, int e) {
    int i = blockIdx.x * blockDim.x + threadIdx.x;
    if (i < e) atomicAdd(&deg[dst[i]], 1);
}

__global__ void k_deg_fin(const int* __restrict__ deg, float* __restrict__ dis,
                          float* __restrict__ dinv, int n) {
    int i = blockIdx.x * blockDim.x + threadIdx.x;
    if (i < n) {
        float d = (float)(deg[i] + 1);   // + self-loop
        dis[i]  = rsqrtf(d);
        dinv[i] = 1.0f / d;
    }
}

// ================= exclusive scan (rowptr) =================

#define SCAN_T 256
#define SCAN_E 1024   // elements per block (4 per thread)

__global__ void k_scan_block(const int* __restrict__ in, int* __restrict__ out,
                             int* __restrict__ bsums, int n) {
    __shared__ int lds[SCAN_T];
    int t = threadIdx.x;
    int base = blockIdx.x * SCAN_E + t * 4;
    int v[4];
#pragma unroll
    for (int j = 0; j < 4; ++j) { int idx = base + j; v[j] = (idx < n) ? in[idx] : 0; }
    int s0 = v[0] + v[1] + v[2] + v[3];
    int val = s0;
    lds[t] = val;
    __syncthreads();
    for (int off = 1; off < SCAN_T; off <<= 1) {
        int tmp = (t >= off) ? lds[t - off] : 0;
        __syncthreads();
        val += tmp;
        lds[t] = val;
        __syncthreads();
    }
    int run = val - s0;   // exclusive prefix of this thread's chunk
#pragma unroll
    for (int j = 0; j < 4; ++j) { int idx = base + j; if (idx < n) out[idx] = run; run += v[j]; }
    if (t == SCAN_T - 1) bsums[blockIdx.x] = val;
}

__global__ void k_scan_carry(int* __restrict__ bsums, int nb, int* __restrict__ rowptr, int n) {
    if (threadIdx.x == 0 && blockIdx.x == 0) {
        int run = 0;
        for (int i = 0; i < nb; ++i) { int t = bsums[i]; bsums[i] = run; run += t; }
        rowptr[n] = run;   // == E
    }
}

__global__ void k_scan_add(int* __restrict__ out, const int* __restrict__ bsums, int n) {
    int i = blockIdx.x * blockDim.x + threadIdx.x;
    if (i < n) out[i] += bsums[i / SCAN_E];
}

// ================= CSR fill (src + norm packed into int2) =================

__global__ void k_csr_fill(const int* __restrict__ src, const int* __restrict__ dst,
                           const float* __restrict__ dis, const int* __restrict__ rowptr,
                           int* __restrict__ cursor, int2* __restrict__ csr, int e) {
    int i = blockIdx.x * blockDim.x + threadIdx.x;
    if (i >= e) return;
    int s = src[i], d = dst[i];
    int p = rowptr[d] + atomicAdd(&cursor[d], 1);
    csr[p] = make_int2(s, __float_as_int(dis[s] * dis[d]));
}

// ================= dense GEMM: H = X @ W (W in LDS) =================

template <int FIN, int FOUT>
__global__ void k_gemm(const float* __restrict__ X, const float* __restrict__ W,
                       float* __restrict__ H, int n_nodes) {
    __shared__ float Ws[FIN * FOUT];
    for (int i = threadIdx.x; i < FIN * FOUT; i += blockDim.x) Ws[i] = W[i];
    __syncthreads();
    constexpr int NPB = 256 / FOUT;
    int node = blockIdx.x * NPB + threadIdx.x / FOUT;
    int f    = threadIdx.x % FOUT;
    if (node >= n_nodes) return;
    const float* xr = X + (size_t)node * FIN;
    float acc = 0.0f;
#pragma unroll
    for (int k = 0; k < FIN; ++k) acc += xr[k] * Ws[k * FOUT + f];
    H[(size_t)node * FOUT + f] = acc;
}

// ================= fused gather-aggregate + self-loop + bias (+BN) + ReLU =================
// one wave per dst node, lane = feature (F=64)

template <bool HAS_BN>
__global__ void k_gather64(const float* __restrict__ H, const int* __restrict__ rowptr,
                           const int2* __restrict__ csr, const float* __restrict__ dinv,
                           const float* __restrict__ b, const float* __restrict__ g,
                           const float* __restrict__ be, const float* __restrict__ m,
                           const float* __restrict__ v, float* __restrict__ out, int n) {
    int node = blockIdx.x * 4 + (threadIdx.x >> 6);
    int lane = threadIdx.x & 63;
    if (node >= n) return;
    int beg = rowptr[node], end = rowptr[node + 1];
    float acc = 0.0f;
    int e = beg;
    for (; e + 1 < end; e += 2) {
        int2 m0 = csr[e];
        int2 m1 = csr[e + 1];
        acc += H[(size_t)m0.x * 64 + lane] * __int_as_float(m0.y);
        acc += H[(size_t)m1.x * 64 + lane] * __int_as_float(m1.y);
    }
    if (e < end) {
        int2 m0 = csr[e];
        acc += H[(size_t)m0.x * 64 + lane] * __int_as_float(m0.y);
    }
    float val = acc + H[(size_t)node * 64 + lane] * dinv[node] + b[lane];
    if (HAS_BN) {
        float s = g[lane] * rsqrtf(v[lane] + BN_EPS);
        val = (val - m[lane]) * s + be[lane];
    }
    out[(size_t)node * 64 + lane] = fmaxf(val, 0.0f);
}

// F=128: one wave per node, float2 per lane
__global__ void k_gather128(const float* __restrict__ H, const int* __restrict__ rowptr,
                            const int2* __restrict__ csr, const float* __restrict__ dinv,
                            const float* __restrict__ b, float* __restrict__ out, int n) {
    int node = blockIdx.x * 4 + (threadIdx.x >> 6);
    int lane = threadIdx.x & 63;
    if (node >= n) return;
    const float2* H2 = (const float2*)H;
    int beg = rowptr[node], end = rowptr[node + 1];
    float2 acc = make_float2(0.0f, 0.0f);
    int e = beg;
    for (; e + 1 < end; e += 2) {
        int2 m0 = csr[e];
        int2 m1 = csr[e + 1];
        float n0 = __int_as_float(m0.y), n1 = __int_as_float(m1.y);
        float2 h0 = H2[(size_t)m0.x * 64 + lane];
        float2 h1 = H2[(size_t)m1.x * 64 + lane];
        acc.x += h0.x * n0 + h1.x * n1;
        acc.y += h0.y * n0 + h1.y * n1;
    }
    if (e < end) {
        int2 m0 = csr[e];
        float n0 = __int_as_float(m0.y);
        float2 h0 = H2[(size_t)m0.x * 64 + lane];
        acc.x += h0.x * n0;
        acc.y += h0.y * n0;
    }
    float di = dinv[node];
    float2 hs = H2[(size_t)node * 64 + lane];
    float vx = acc.x + hs.x * di + b[lane * 2];
    float vy = acc.y + hs.y * di + b[lane * 2 + 1];
    float2 o = make_float2(fmaxf(vx, 0.0f), fmaxf(vy, 0.0f));
    ((float2*)out)[(size_t)node * 64 + lane] = o;
}

// ================= pool (batch is sorted: accumulate, flush on change) =================

__global__ void k_pool(const float* __restrict__ H, const int* __restrict__ batch,
                       float* __restrict__ sums, int n) {
    int f = threadIdx.x;            // 0..127
    int base = blockIdx.x * 32;
    if (base >= n) return;
    int endn = min(base + 32, n);
    int cur = batch[base];
    float acc = 0.0f;
    for (int node = base; node < endn; ++node) {
        int bb = batch[node];
        if (bb != cur) { atomicAdd(&sums[cur * 128 + f], acc); acc = 0.0f; cur = bb; }
        acc += H[(size_t)node * 128 + f];
    }
    atomicAdd(&sums[cur * 128 + f], acc);
}

__global__ void k_cnt(const int* __restrict__ batch, float* __restrict__ cnt, int n) {
    int i = blockIdx.x * blockDim.x + threadIdx.x;
    if (i < n) atomicAdd(&cnt[batch[i]], 1.0f);
}

__global__ void k_pool_div(const float* __restrict__ sums, const float* __restrict__ cnt,
                           float* __restrict__ out, int nB) {
    int i = blockIdx.x * blockDim.x + threadIdx.x;
    if (i < nB * 128) out[i] = sums[i] / fmaxf(cnt[i >> 7], 1.0f);
}

// ================= launch =================

extern "C" void kernel_launch(void* const* d_in, const int* in_sizes, int n_in,
                              void* d_out, int out_size, void* d_ws, size_t ws_size,
                              hipStream_t stream) {
    const float* x   = (const float*)d_in[0];
    const int*   ei  = (const int*)d_in[1];
    const int*   bat = (const int*)d_in[2];
    const float* W1  = (const float*)d_in[3];
    const float* b1  = (const float*)d_in[4];
    const float* W2  = (const float*)d_in[5];
    const float* b2  = (const float*)d_in[6];
    const float* W3  = (const float*)d_in[7];
    const float* b3  = (const float*)d_in[8];
    const float* g1  = (const float*)d_in[9];
    const float* be1 = (const float*)d_in[10];
    const float* m1  = (const float*)d_in[11];
    const float* v1  = (const float*)d_in[12];
    const float* g2  = (const float*)d_in[13];
    const float* be2 = (const float*)d_in[14];
    const float* m2  = (const float*)d_in[15];
    const float* v2  = (const float*)d_in[16];

    const int N = in_sizes[0] / 22;
    const int E = in_sizes[1] / 2;
    const int B = out_size / 128;
    const int* src = ei;
    const int* dst = ei + E;

    // workspace layout (4-byte units)
    char* w = (char*)d_ws;
    int*   deg    = (int*)w;                 w += (size_t)N * 4;
    int*   rowptr = (int*)w;                 w += (size_t)(N + 1) * 4;
    int*   cursor = (int*)w;                 w += (size_t)N * 4;
    int*   bsums  = (int*)w;                 w += 512;
    float* dis    = (float*)w;               w += (size_t)N * 4;
    float* dinv   = (float*)w;               w += (size_t)N * 4;
    int2*  csr    = (int2*)w;                w += (size_t)E * 8;
    float* bufA   = (float*)w;               w += (size_t)N * 128 * 4;
    float* bufB   = (float*)w;               w += (size_t)N * 128 * 4;
    float* sums   = (float*)w;               w += (size_t)B * 128 * 4;
    float* cnt    = (float*)w;

    const int T = 256;
    auto blk = [](long long n, int t) { return (int)((n + t - 1) / t); };

    // ---- degree histogram + norms ----
    hipMemsetAsync(deg, 0, (size_t)N * 4, stream);
    k_hist<<<blk(E, T), T, 0, stream>>>(dst, deg, E);
    k_deg_fin<<<blk(N, T), T, 0, stream>>>(deg, dis, dinv, N);

    // ---- rowptr = exclusive scan of deg ----
    int nb = (N + SCAN_E - 1) / SCAN_E;
    k_scan_block<<<nb, SCAN_T, 0, stream>>>(deg, rowptr, bsums, N);
    k_scan_carry<<<1, 64, 0, stream>>>(bsums, nb, rowptr, N);
    k_scan_add<<<blk(N, T), T, 0, stream>>>(rowptr, bsums, N);

    // ---- CSR fill ----
    hipMemsetAsync(cursor, 0, (size_t)N * 4, stream);
    k_csr_fill<<<blk(E, T), T, 0, stream>>>(src, dst, dis, rowptr, cursor, csr, E);

    // ---- layer 1: 22 -> 64, BN1, ReLU ----
    k_gemm<22, 64><<<blk(N, 4), T, 0, stream>>>(x, W1, bufA, N);
    k_gather64<true><<<blk(N, 4), T, 0, stream>>>(bufA, rowptr, csr, dinv, b1,
                                                  g1, be1, m1, v1, bufB, N);

    // ---- layer 2: 64 -> 64, BN2, ReLU ----
    k_gemm<64, 64><<<blk(N, 4), T, 0, stream>>>(bufB, W2, bufA, N);
    k_gather64<true><<<blk(N, 4), T, 0, stream>>>(bufA, rowptr, csr, dinv, b2,
                                                  g2, be2, m2, v2, bufB, N);

    // ---- layer 3: 64 -> 128, ReLU ----
    k_gemm<64, 128><<<blk(N, 2), T, 0, stream>>>(bufB, W3, bufA, N);
    k_gather128<<<blk(N, 4), T, 0, stream>>>(bufA, rowptr, csr, dinv, b3, bufB, N);

    // ---- global mean pool ----
    hipMemsetAsync(sums, 0, (size_t)(B * 128 + B) * sizeof(float), stream);
    k_pool<<<blk(N, 32), 128, 0, stream>>>(bufB, bat, sums, N);
    k_cnt<<<blk(N, T), T, 0, stream>>>(bat, cnt, N);
    k_pool_div<<<blk(B * 128, T), T, 0, stream>>>(sums, cnt, (float*)d_out, B);
}

// Round 3
// 867.187 us; speedup vs baseline: 7.2066x; 1.3916x over previous
//
#include <hip/hip_runtime.h>

#define BN_EPS 1e-5f

// ================= degree histogram / norms =================

__global__ void k_hist(const int* __restrict__ dst, int* __restrict__ deg, int e) {
    int i = blockIdx.x * blockDim.x + threadIdx.x;
    if (i < e) atomicAdd(&deg[dst[i]], 1);
}

__global__ void k_deg_fin(const int* __restrict__ deg, float* __restrict__ dis,
                          float* __restrict__ dinv, int n) {
    int i = blockIdx.x * blockDim.x + threadIdx.x;
    if (i < n) {
        float d = (float)(deg[i] + 1);   // + self-loop
        dis[i]  = rsqrtf(d);
        dinv[i] = 1.0f / d;
    }
}

// ================= exclusive scan (rowptr) =================

#define SCAN_T 256
#define SCAN_E 1024

__global__ void k_scan_block(const int* __restrict__ in, int* __restrict__ out,
                             int* __restrict__ bsums, int n) {
    __shared__ int lds[SCAN_T];
    int t = threadIdx.x;
    int base = blockIdx.x * SCAN_E + t * 4;
    int v[4];
#pragma unroll
    for (int j = 0; j < 4; ++j) { int idx = base + j; v[j] = (idx < n) ? in[idx] : 0; }
    int s0 = v[0] + v[1] + v[2] + v[3];
    int val = s0;
    lds[t] = val;
    __syncthreads();
    for (int off = 1; off < SCAN_T; off <<= 1) {
        int tmp = (t >= off) ? lds[t - off] : 0;
        __syncthreads();
        val += tmp;
        lds[t] = val;
        __syncthreads();
    }
    int run = val - s0;
#pragma unroll
    for (int j = 0; j < 4; ++j) { int idx = base + j; if (idx < n) out[idx] = run; run += v[j]; }
    if (t == SCAN_T - 1) bsums[blockIdx.x] = val;
}

__global__ void k_scan_carry(int* __restrict__ bsums, int nb, int* __restrict__ rowptr, int n) {
    if (threadIdx.x == 0 && blockIdx.x == 0) {
        int run = 0;
        for (int i = 0; i < nb; ++i) { int t = bsums[i]; bsums[i] = run; run += t; }
        rowptr[n] = run;
    }
}

__global__ void k_scan_add(int* __restrict__ out, const int* __restrict__ bsums, int n) {
    int i = blockIdx.x * blockDim.x + threadIdx.x;
    if (i < n) out[i] += bsums[i / SCAN_E];
}

// ================= CSR fill (src + norm packed) =================

__global__ void k_csr_fill(const int* __restrict__ src, const int* __restrict__ dst,
                           const float* __restrict__ dis, const int* __restrict__ rowptr,
                           int* __restrict__ cursor, int2* __restrict__ csr, int e) {
    int i = blockIdx.x * blockDim.x + threadIdx.x;
    if (i >= e) return;
    int s = src[i], d = dst[i];
    int p = rowptr[d] + atomicAdd(&cursor[d], 1);
    csr[p] = make_int2(s, __float_as_int(dis[s] * dis[d]));
}

// ================= gather-aggregate (raw features, pre-GEMM) =================
// 22-dim input X -> agg with stride 24 (cols 22,23 zeroed). 32-thread group per node.

__global__ void k_gather22(const float* __restrict__ X, const int* __restrict__ rowptr,
                           const int2* __restrict__ csr, const float* __restrict__ dinv,
                           float* __restrict__ out, int n) {
    int node = blockIdx.x * 8 + (threadIdx.x >> 5);
    int lane = threadIdx.x & 31;
    if (node >= n) return;
    bool act = lane < 22;
    int beg = rowptr[node], end = rowptr[node + 1];
    float acc = 0.0f;
    int e = beg;
    for (; e + 1 < end; e += 2) {
        int2 m0 = csr[e];
        int2 m1 = csr[e + 1];
        if (act) {
            acc += X[(size_t)m0.x * 22 + lane] * __int_as_float(m0.y);
            acc += X[(size_t)m1.x * 22 + lane] * __int_as_float(m1.y);
        }
    }
    if (e < end) {
        int2 m0 = csr[e];
        if (act) acc += X[(size_t)m0.x * 22 + lane] * __int_as_float(m0.y);
    }
    if (lane < 24) {
        float val = act ? (acc + X[(size_t)node * 22 + lane] * dinv[node]) : 0.0f;
        out[(size_t)node * 24 + lane] = val;
    }
}

// 64-dim: one wave per node, lane = feature
__global__ void k_gather64(const float* __restrict__ H, const int* __restrict__ rowptr,
                           const int2* __restrict__ csr, const float* __restrict__ dinv,
                           float* __restrict__ out, int n) {
    int node = blockIdx.x * 4 + (threadIdx.x >> 6);
    int lane = threadIdx.x & 63;
    if (node >= n) return;
    int beg = rowptr[node], end = rowptr[node + 1];
    float acc = 0.0f;
    int e = beg;
    for (; e + 1 < end; e += 2) {
        int2 m0 = csr[e];
        int2 m1 = csr[e + 1];
        acc += H[(size_t)m0.x * 64 + lane] * __int_as_float(m0.y);
        acc += H[(size_t)m1.x * 64 + lane] * __int_as_float(m1.y);
    }
    if (e < end) {
        int2 m0 = csr[e];
        acc += H[(size_t)m0.x * 64 + lane] * __int_as_float(m0.y);
    }
    out[(size_t)node * 64 + lane] = acc + H[(size_t)node * 64 + lane] * dinv[node];
}

// ================= fused GEMM + bias + BN + ReLU =================
// one node per thread; X row in VGPRs; W in LDS (b128 broadcast reads).
// out[node,f] = ReLU( (P@W)[node,f] * A[f] + C[f] )
//   A = g*rsqrt(v+eps) (or 1), C = be + (b-m)*A (or b)

template <int FIN_PAD, int FOUT, bool HAS_BN>
__global__ void k_gemm_fused(const float* __restrict__ P, const float* __restrict__ W,
                             int fin_real, const float* __restrict__ b,
                             const float* __restrict__ g, const float* __restrict__ be,
                             const float* __restrict__ m, const float* __restrict__ v,
                             float* __restrict__ out, int n) {
    __shared__ float Ws[FIN_PAD * FOUT];
    __shared__ float Af[FOUT], Cf[FOUT];
    for (int i = threadIdx.x; i < FIN_PAD * FOUT; i += 256) {
        int r = i / FOUT, c = i % FOUT;
        Ws[i] = (r < fin_real) ? W[r * FOUT + c] : 0.0f;
    }
    for (int f = threadIdx.x; f < FOUT; f += 256) {
        float A = HAS_BN ? g[f] * rsqrtf(v[f] + BN_EPS) : 1.0f;
        Af[f] = A;
        Cf[f] = HAS_BN ? be[f] + (b[f] - m[f]) * A : b[f];
    }
    __syncthreads();
    int node = blockIdx.x * 256 + threadIdx.x;
    if (node >= n) return;

    float4 xr[FIN_PAD / 4];
    const float4* p4 = (const float4*)(P + (size_t)node * FIN_PAD);
#pragma unroll
    for (int i = 0; i < FIN_PAD / 4; ++i) xr[i] = p4[i];
    const float* x = (const float*)xr;

    float4* o4 = (float4*)(out + (size_t)node * FOUT);
    for (int c0 = 0; c0 < FOUT; c0 += 16) {
        float4 acc0 = make_float4(0, 0, 0, 0), acc1 = acc0, acc2 = acc0, acc3 = acc0;
#pragma unroll
        for (int k = 0; k < FIN_PAD; ++k) {
            float xv = x[k];
            const float4* wr = (const float4*)(Ws + k * FOUT + c0);
            float4 w0 = wr[0], w1 = wr[1], w2 = wr[2], w3 = wr[3];
            acc0.x += xv * w0.x; acc0.y += xv * w0.y; acc0.z += xv * w0.z; acc0.w += xv * w0.w;
            acc1.x += xv * w1.x; acc1.y += xv * w1.y; acc1.z += xv * w1.z; acc1.w += xv * w1.w;
            acc2.x += xv * w2.x; acc2.y += xv * w2.y; acc2.z += xv * w2.z; acc2.w += xv * w2.w;
            acc3.x += xv * w3.x; acc3.y += xv * w3.y; acc3.z += xv * w3.z; acc3.w += xv * w3.w;
        }
        float4 accs[4] = {acc0, acc1, acc2, acc3};
#pragma unroll
        for (int j = 0; j < 4; ++j) {
            int f = c0 + j * 4;
            float4 r;
            r.x = fmaxf(accs[j].x * Af[f + 0] + Cf[f + 0], 0.0f);
            r.y = fmaxf(accs[j].y * Af[f + 1] + Cf[f + 1], 0.0f);
            r.z = fmaxf(accs[j].z * Af[f + 2] + Cf[f + 2], 0.0f);
            r.w = fmaxf(accs[j].w * Af[f + 3] + Cf[f + 3], 0.0f);
            o4[(c0 / 4) + j] = r;
        }
    }
}

// ================= pool =================

__global__ void k_pool(const float* __restrict__ H, const int* __restrict__ batch,
                       float* __restrict__ sums, int n) {
    int f = threadIdx.x;            // 0..127
    int base = blockIdx.x * 32;
    if (base >= n) return;
    int endn = min(base + 32, n);
    int cur = batch[base];
    float acc = 0.0f;
    for (int node = base; node < endn; ++node) {
        int bb = batch[node];
        if (bb != cur) { atomicAdd(&sums[cur * 128 + f], acc); acc = 0.0f; cur = bb; }
        acc += H[(size_t)node * 128 + f];
    }
    atomicAdd(&sums[cur * 128 + f], acc);
}

__global__ void k_cnt(const int* __restrict__ batch, float* __restrict__ cnt, int n) {
    int i = blockIdx.x * blockDim.x + threadIdx.x;
    if (i < n) atomicAdd(&cnt[batch[i]], 1.0f);
}

__global__ void k_pool_div(const float* __restrict__ sums, const float* __restrict__ cnt,
                           float* __restrict__ out, int nB) {
    int i = blockIdx.x * blockDim.x + threadIdx.x;
    if (i < nB * 128) out[i] = sums[i] / fmaxf(cnt[i >> 7], 1.0f);
}

// ================= launch =================

extern "C" void kernel_launch(void* const* d_in, const int* in_sizes, int n_in,
                              void* d_out, int out_size, void* d_ws, size_t ws_size,
                              hipStream_t stream) {
    const float* x   = (const float*)d_in[0];
    const int*   ei  = (const int*)d_in[1];
    const int*   bat = (const int*)d_in[2];
    const float* W1  = (const float*)d_in[3];
    const float* b1  = (const float*)d_in[4];
    const float* W2  = (const float*)d_in[5];
    const float* b2  = (const float*)d_in[6];
    const float* W3  = (const float*)d_in[7];
    const float* b3  = (const float*)d_in[8];
    const float* g1  = (const float*)d_in[9];
    const float* be1 = (const float*)d_in[10];
    const float* m1  = (const float*)d_in[11];
    const float* v1  = (const float*)d_in[12];
    const float* g2  = (const float*)d_in[13];
    const float* be2 = (const float*)d_in[14];
    const float* m2  = (const float*)d_in[15];
    const float* v2  = (const float*)d_in[16];

    const int N = in_sizes[0] / 22;
    const int E = in_sizes[1] / 2;
    const int B = out_size / 128;
    const int* src = ei;
    const int* dst = ei + E;

    // workspace layout, 256B-aligned regions
    size_t off = 0;
    char* base = (char*)d_ws;
    auto alloc = [&](size_t bytes) -> void* {
        void* p = base + off;
        off = (off + bytes + 255) & ~(size_t)255;
        return p;
    };
    int*   deg    = (int*)alloc((size_t)N * 4);
    int*   rowptr = (int*)alloc((size_t)(N + 1) * 4);
    int*   cursor = (int*)alloc((size_t)N * 4);
    int*   bsums  = (int*)alloc(512);
    float* dis    = (float*)alloc((size_t)N * 4);
    float* dinv   = (float*)alloc((size_t)N * 4);
    int2*  csr    = (int2*)alloc((size_t)E * 8);
    float* bufA   = (float*)alloc((size_t)N * 128 * 4);
    float* bufB   = (float*)alloc((size_t)N * 128 * 4);
    float* sums   = (float*)alloc((size_t)B * 128 * 4 + (size_t)B * 4);
    float* cnt    = sums + (size_t)B * 128;

    const int T = 256;
    auto blk = [](long long n, int t) { return (int)((n + t - 1) / t); };

    // ---- CSR build ----
    hipMemsetAsync(deg, 0, (size_t)N * 4, stream);
    k_hist<<<blk(E, T), T, 0, stream>>>(dst, deg, E);
    k_deg_fin<<<blk(N, T), T, 0, stream>>>(deg, dis, dinv, N);
    int nb = (N + SCAN_E - 1) / SCAN_E;
    k_scan_block<<<nb, SCAN_T, 0, stream>>>(deg, rowptr, bsums, N);
    k_scan_carry<<<1, 64, 0, stream>>>(bsums, nb, rowptr, N);
    k_scan_add<<<blk(N, T), T, 0, stream>>>(rowptr, bsums, N);
    hipMemsetAsync(cursor, 0, (size_t)N * 4, stream);
    k_csr_fill<<<blk(E, T), T, 0, stream>>>(src, dst, dis, rowptr, cursor, csr, E);

    // ---- layer 1: agg(X) [N x 24 padded] -> gemm 22->64 + BN1 + ReLU ----
    k_gather22<<<blk(N, 8), T, 0, stream>>>(x, rowptr, csr, dinv, bufA, N);
    k_gemm_fused<24, 64, true><<<blk(N, T), T, 0, stream>>>(
        bufA, W1, 22, b1, g1, be1, m1, v1, bufB, N);

    // ---- layer 2: agg(h1) -> gemm 64->64 + BN2 + ReLU ----
    k_gather64<<<blk(N, 4), T, 0, stream>>>(bufB, rowptr, csr, dinv, bufA, N);
    k_gemm_fused<64, 64, true><<<blk(N, T), T, 0, stream>>>(
        bufA, W2, 64, b2, g2, be2, m2, v2, bufB, N);

    // ---- layer 3: agg(h2) -> gemm 64->128 + ReLU ----
    k_gather64<<<blk(N, 4), T, 0, stream>>>(bufB, rowptr, csr, dinv, bufA, N);
    k_gemm_fused<64, 128, false><<<blk(N, T), T, 0, stream>>>(
        bufA, W3, 64, b3, nullptr, nullptr, nullptr, nullptr, bufB, N);

    // ---- global mean pool ----
    hipMemsetAsync(sums, 0, (size_t)(B * 128 + B) * sizeof(float), stream);
    k_pool<<<blk(N, 32), 128, 0, stream>>>(bufB, bat, sums, N);
    k_cnt<<<blk(N, T), T, 0, stream>>>(bat, cnt, N);
    k_pool_div<<<blk(B * 128, T), T, 0, stream>>>(sums, cnt, (float*)d_out, B);
}

// Round 4
// 668.761 us; speedup vs baseline: 9.3448x; 1.2967x over previous
//
#include <hip/hip_runtime.h>

#define BN_EPS 1e-5f

// ================= degree histogram / norms =================

__global__ void k_hist(const int* __restrict__ dst, int* __restrict__ deg, int e) {
    int i = blockIdx.x * blockDim.x + threadIdx.x;
    if (i < e) atomicAdd(&deg[dst[i]], 1);
}

__global__ void k_deg_fin(const int* __restrict__ deg, float* __restrict__ dis,
                          float* __restrict__ dinv, int n) {
    int i = blockIdx.x * blockDim.x + threadIdx.x;
    if (i < n) {
        float d = (float)(deg[i] + 1);   // + self-loop
        dis[i]  = rsqrtf(d);
        dinv[i] = 1.0f / d;
    }
}

// ================= exclusive scan (rowptr) =================

#define SCAN_T 256
#define SCAN_E 1024

__global__ void k_scan_block(const int* __restrict__ in, int* __restrict__ out,
                             int* __restrict__ bsums, int n) {
    __shared__ int lds[SCAN_T];
    int t = threadIdx.x;
    int base = blockIdx.x * SCAN_E + t * 4;
    int v[4];
#pragma unroll
    for (int j = 0; j < 4; ++j) { int idx = base + j; v[j] = (idx < n) ? in[idx] : 0; }
    int s0 = v[0] + v[1] + v[2] + v[3];
    int val = s0;
    lds[t] = val;
    __syncthreads();
    for (int off = 1; off < SCAN_T; off <<= 1) {
        int tmp = (t >= off) ? lds[t - off] : 0;
        __syncthreads();
        val += tmp;
        lds[t] = val;
        __syncthreads();
    }
    int run = val - s0;
#pragma unroll
    for (int j = 0; j < 4; ++j) { int idx = base + j; if (idx < n) out[idx] = run; run += v[j]; }
    if (t == SCAN_T - 1) bsums[blockIdx.x] = val;
}

__global__ void k_scan_carry(int* __restrict__ bsums, int nb, int* __restrict__ rowptr, int n) {
    if (threadIdx.x == 0 && blockIdx.x == 0) {
        int run = 0;
        for (int i = 0; i < nb; ++i) { int t = bsums[i]; bsums[i] = run; run += t; }
        rowptr[n] = run;
    }
}

__global__ void k_scan_add(int* __restrict__ out, const int* __restrict__ bsums, int n) {
    int i = blockIdx.x * blockDim.x + threadIdx.x;
    if (i < n) out[i] += bsums[i / SCAN_E];
}

// ================= CSR fill (src + norm packed) =================

__global__ void k_csr_fill(const int* __restrict__ src, const int* __restrict__ dst,
                           const float* __restrict__ dis, const int* __restrict__ rowptr,
                           int* __restrict__ cursor, int2* __restrict__ csr, int e) {
    int i = blockIdx.x * blockDim.x + threadIdx.x;
    if (i >= e) return;
    int s = src[i], d = dst[i];
    int p = rowptr[d] + atomicAdd(&cursor[d], 1);
    csr[p] = make_int2(s, __float_as_int(dis[s] * dis[d]));
}

// ================= gather-aggregate (raw features, pre-GEMM) =================

__global__ void k_gather22(const float* __restrict__ X, const int* __restrict__ rowptr,
                           const int2* __restrict__ csr, const float* __restrict__ dinv,
                           float* __restrict__ out, int n) {
    int node = blockIdx.x * 8 + (threadIdx.x >> 5);
    int lane = threadIdx.x & 31;
    if (node >= n) return;
    bool act = lane < 22;
    int beg = rowptr[node], end = rowptr[node + 1];
    float acc = 0.0f;
    int e = beg;
    for (; e + 1 < end; e += 2) {
        int2 m0 = csr[e];
        int2 m1 = csr[e + 1];
        if (act) {
            acc += X[(size_t)m0.x * 22 + lane] * __int_as_float(m0.y);
            acc += X[(size_t)m1.x * 22 + lane] * __int_as_float(m1.y);
        }
    }
    if (e < end) {
        int2 m0 = csr[e];
        if (act) acc += X[(size_t)m0.x * 22 + lane] * __int_as_float(m0.y);
    }
    if (lane < 24) {
        float val = act ? (acc + X[(size_t)node * 22 + lane] * dinv[node]) : 0.0f;
        out[(size_t)node * 24 + lane] = val;
    }
}

// 64-dim: one wave per node, lane = feature
__global__ void k_gather64(const float* __restrict__ H, const int* __restrict__ rowptr,
                           const int2* __restrict__ csr, const float* __restrict__ dinv,
                           float* __restrict__ out, int n) {
    int node = blockIdx.x * 4 + (threadIdx.x >> 6);
    int lane = threadIdx.x & 63;
    if (node >= n) return;
    int beg = rowptr[node], end = rowptr[node + 1];
    float acc = 0.0f;
    int e = beg;
    for (; e + 1 < end; e += 2) {
        int2 m0 = csr[e];
        int2 m1 = csr[e + 1];
        acc += H[(size_t)m0.x * 64 + lane] * __int_as_float(m0.y);
        acc += H[(size_t)m1.x * 64 + lane] * __int_as_float(m1.y);
    }
    if (e < end) {
        int2 m0 = csr[e];
        acc += H[(size_t)m0.x * 64 + lane] * __int_as_float(m0.y);
    }
    out[(size_t)node * 64 + lane] = acc + H[(size_t)node * 64 + lane] * dinv[node];
}

// ================= fused GEMM + bias + BN + ReLU =================

template <int FIN_PAD, int FOUT, bool HAS_BN>
__global__ void k_gemm_fused(const float* __restrict__ P, const float* __restrict__ W,
                             int fin_real, const float* __restrict__ b,
                             const float* __restrict__ g, const float* __restrict__ be,
                             const float* __restrict__ m, const float* __restrict__ v,
                             float* __restrict__ out, int n) {
    __shared__ float Ws[FIN_PAD * FOUT];
    __shared__ float Af[FOUT], Cf[FOUT];
    for (int i = threadIdx.x; i < FIN_PAD * FOUT; i += 256) {
        int r = i / FOUT, c = i % FOUT;
        Ws[i] = (r < fin_real) ? W[r * FOUT + c] : 0.0f;
    }
    for (int f = threadIdx.x; f < FOUT; f += 256) {
        float A = HAS_BN ? g[f] * rsqrtf(v[f] + BN_EPS) : 1.0f;
        Af[f] = A;
        Cf[f] = HAS_BN ? be[f] + (b[f] - m[f]) * A : b[f];
    }
    __syncthreads();
    int node = blockIdx.x * 256 + threadIdx.x;
    if (node >= n) return;

    float4 xr[FIN_PAD / 4];
    const float4* p4 = (const float4*)(P + (size_t)node * FIN_PAD);
#pragma unroll
    for (int i = 0; i < FIN_PAD / 4; ++i) xr[i] = p4[i];
    const float* x = (const float*)xr;

    float4* o4 = (float4*)(out + (size_t)node * FOUT);
    for (int c0 = 0; c0 < FOUT; c0 += 16) {
        float4 acc0 = make_float4(0, 0, 0, 0), acc1 = acc0, acc2 = acc0, acc3 = acc0;
#pragma unroll
        for (int k = 0; k < FIN_PAD; ++k) {
            float xv = x[k];
            const float4* wr = (const float4*)(Ws + k * FOUT + c0);
            float4 w0 = wr[0], w1 = wr[1], w2 = wr[2], w3 = wr[3];
            acc0.x += xv * w0.x; acc0.y += xv * w0.y; acc0.z += xv * w0.z; acc0.w += xv * w0.w;
            acc1.x += xv * w1.x; acc1.y += xv * w1.y; acc1.z += xv * w1.z; acc1.w += xv * w1.w;
            acc2.x += xv * w2.x; acc2.y += xv * w2.y; acc2.z += xv * w2.z; acc2.w += xv * w2.w;
            acc3.x += xv * w3.x; acc3.y += xv * w3.y; acc3.z += xv * w3.z; acc3.w += xv * w3.w;
        }
        float4 accs[4] = {acc0, acc1, acc2, acc3};
#pragma unroll
        for (int j = 0; j < 4; ++j) {
            int f = c0 + j * 4;
            float4 r;
            r.x = fmaxf(accs[j].x * Af[f + 0] + Cf[f + 0], 0.0f);
            r.y = fmaxf(accs[j].y * Af[f + 1] + Cf[f + 1], 0.0f);
            r.z = fmaxf(accs[j].z * Af[f + 2] + Cf[f + 2], 0.0f);
            r.w = fmaxf(accs[j].w * Af[f + 3] + Cf[f + 3], 0.0f);
            o4[(c0 / 4) + j] = r;
        }
    }
}

// ================= pool =================

__global__ void k_pool(const float* __restrict__ H, const int* __restrict__ batch,
                       float* __restrict__ sums, int n) {
    int f = threadIdx.x;            // 0..127
    int base = blockIdx.x * 32;
    if (base >= n) return;
    int endn = min(base + 32, n);
    int cur = batch[base];
    float acc = 0.0f;
    for (int node = base; node < endn; ++node) {
        int bb = batch[node];
        if (bb != cur) { atomicAdd(&sums[cur * 128 + f], acc); acc = 0.0f; cur = bb; }
        acc += H[(size_t)node * 128 + f];
    }
    atomicAdd(&sums[cur * 128 + f], acc);
}

// batch is sorted: counts via binary search, no atomics
__global__ void k_cnt_bs(const int* __restrict__ batch, float* __restrict__ cnt,
                         int n, int nB) {
    int b = blockIdx.x * blockDim.x + threadIdx.x;
    if (b >= nB) return;
    int lo = 0, hi = n;
    while (lo < hi) { int mid = (lo + hi) >> 1; if (batch[mid] < b) lo = mid + 1; else hi = mid; }
    int start = lo;
    lo = 0; hi = n;
    while (lo < hi) { int mid = (lo + hi) >> 1; if (batch[mid] < b + 1) lo = mid + 1; else hi = mid; }
    cnt[b] = (float)(lo - start);
}

__global__ void k_pool_div(const float* __restrict__ sums, const float* __restrict__ cnt,
                           float* __restrict__ out, int nB) {
    int i = blockIdx.x * blockDim.x + threadIdx.x;
    if (i < nB * 128) out[i] = sums[i] / fmaxf(cnt[i >> 7], 1.0f);
}

// ================= launch =================

extern "C" void kernel_launch(void* const* d_in, const int* in_sizes, int n_in,
                              void* d_out, int out_size, void* d_ws, size_t ws_size,
                              hipStream_t stream) {
    const float* x   = (const float*)d_in[0];
    const int*   ei  = (const int*)d_in[1];
    const int*   bat = (const int*)d_in[2];
    const float* W1  = (const float*)d_in[3];
    const float* b1  = (const float*)d_in[4];
    const float* W2  = (const float*)d_in[5];
    const float* b2  = (const float*)d_in[6];
    const float* W3  = (const float*)d_in[7];
    const float* b3  = (const float*)d_in[8];
    const float* g1  = (const float*)d_in[9];
    const float* be1 = (const float*)d_in[10];
    const float* m1  = (const float*)d_in[11];
    const float* v1  = (const float*)d_in[12];
    const float* g2  = (const float*)d_in[13];
    const float* be2 = (const float*)d_in[14];
    const float* m2  = (const float*)d_in[15];
    const float* v2  = (const float*)d_in[16];

    const int N = in_sizes[0] / 22;
    const int E = in_sizes[1] / 2;
    const int B = out_size / 128;
    const int* src = ei;
    const int* dst = ei + E;

    size_t off = 0;
    char* base = (char*)d_ws;
    auto alloc = [&](size_t bytes) -> void* {
        void* p = base + off;
        off = (off + bytes + 255) & ~(size_t)255;
        return p;
    };
    int*   deg    = (int*)alloc((size_t)N * 4);
    int*   rowptr = (int*)alloc((size_t)(N + 1) * 4);
    int*   cursor = (int*)alloc((size_t)N * 4);
    int*   bsums  = (int*)alloc(512);
    float* dis    = (float*)alloc((size_t)N * 4);
    float* dinv   = (float*)alloc((size_t)N * 4);
    int2*  csr    = (int2*)alloc((size_t)E * 8);
    float* bufA   = (float*)alloc((size_t)N * 128 * 4);
    float* bufB   = (float*)alloc((size_t)N * 128 * 4);
    float* sums   = (float*)alloc((size_t)B * 128 * 4 + (size_t)B * 4);
    float* cnt    = sums + (size_t)B * 128;

    const int T = 256;
    auto blk = [](long long n, int t) { return (int)((n + t - 1) / t); };

    // ---- CSR build ----
    hipMemsetAsync(deg, 0, (size_t)N * 4, stream);
    k_hist<<<blk(E, T), T, 0, stream>>>(dst, deg, E);
    k_deg_fin<<<blk(N, T), T, 0, stream>>>(deg, dis, dinv, N);
    int nb = (N + SCAN_E - 1) / SCAN_E;
    k_scan_block<<<nb, SCAN_T, 0, stream>>>(deg, rowptr, bsums, N);
    k_scan_carry<<<1, 64, 0, stream>>>(bsums, nb, rowptr, N);
    k_scan_add<<<blk(N, T), T, 0, stream>>>(rowptr, bsums, N);
    hipMemsetAsync(cursor, 0, (size_t)N * 4, stream);
    k_csr_fill<<<blk(E, T), T, 0, stream>>>(src, dst, dis, rowptr, cursor, csr, E);

    // ---- layer 1: agg(X) [N x 24 padded] -> gemm 22->64 + BN1 + ReLU ----
    k_gather22<<<blk(N, 8), T, 0, stream>>>(x, rowptr, csr, dinv, bufA, N);
    k_gemm_fused<24, 64, true><<<blk(N, T), T, 0, stream>>>(
        bufA, W1, 22, b1, g1, be1, m1, v1, bufB, N);

    // ---- layer 2: agg(h1) -> gemm 64->64 + BN2 + ReLU ----
    k_gather64<<<blk(N, 4), T, 0, stream>>>(bufB, rowptr, csr, dinv, bufA, N);
    k_gemm_fused<64, 64, true><<<blk(N, T), T, 0, stream>>>(
        bufA, W2, 64, b2, g2, be2, m2, v2, bufB, N);

    // ---- layer 3: agg(h2) -> gemm 64->128 + ReLU ----
    k_gather64<<<blk(N, 4), T, 0, stream>>>(bufB, rowptr, csr, dinv, bufA, N);
    k_gemm_fused<64, 128, false><<<blk(N, T), T, 0, stream>>>(
        bufA, W3, 64, b3, nullptr, nullptr, nullptr, nullptr, bufB, N);

    // ---- global mean pool ----
    hipMemsetAsync(sums, 0, (size_t)B * 128 * sizeof(float), stream);
    k_pool<<<blk(N, 32), 128, 0, stream>>>(bufB, bat, sums, N);
    k_cnt_bs<<<1, 256, 0, stream>>>(bat, cnt, N, B);
    k_pool_div<<<blk(B * 128, T), T, 0, stream>>>(sums, cnt, (float*)d_out, B);
}

// Round 5
// 592.648 us; speedup vs baseline: 10.5449x; 1.1284x over previous
//
#include <hip/hip_runtime.h>

#define BN_EPS 1e-5f

// ================= degree histogram / norms =================

__global__ void k_hist(const int* __restrict__ dst, int* __restrict__ deg, int e) {
    int i = blockIdx.x * blockDim.x + threadIdx.x;
    if (i < e) atomicAdd(&deg[dst[i]], 1);
}

__global__ void k_deg_fin(const int* __restrict__ deg, float* __restrict__ dis,
                          float* __restrict__ dinv, int n) {
    int i = blockIdx.x * blockDim.x + threadIdx.x;
    if (i < n) {
        float d = (float)(deg[i] + 1);   // + self-loop
        dis[i]  = rsqrtf(d);
        dinv[i] = 1.0f / d;
    }
}

// ================= exclusive scan (rowptr) =================

#define SCAN_T 256
#define SCAN_E 1024

__global__ void k_scan_block(const int* __restrict__ in, int* __restrict__ out,
                             int* __restrict__ bsums, int n) {
    __shared__ int lds[SCAN_T];
    int t = threadIdx.x;
    int base = blockIdx.x * SCAN_E + t * 4;
    int v[4];
#pragma unroll
    for (int j = 0; j < 4; ++j) { int idx = base + j; v[j] = (idx < n) ? in[idx] : 0; }
    int s0 = v[0] + v[1] + v[2] + v[3];
    int val = s0;
    lds[t] = val;
    __syncthreads();
    for (int off = 1; off < SCAN_T; off <<= 1) {
        int tmp = (t >= off) ? lds[t - off] : 0;
        __syncthreads();
        val += tmp;
        lds[t] = val;
        __syncthreads();
    }
    int run = val - s0;
#pragma unroll
    for (int j = 0; j < 4; ++j) { int idx = base + j; if (idx < n) out[idx] = run; run += v[j]; }
    if (t == SCAN_T - 1) bsums[blockIdx.x] = val;
}

__global__ void k_scan_carry(int* __restrict__ bsums, int nb, int* __restrict__ rowptr, int n) {
    if (threadIdx.x == 0 && blockIdx.x == 0) {
        int run = 0;
        for (int i = 0; i < nb; ++i) { int t = bsums[i]; bsums[i] = run; run += t; }
        rowptr[n] = run;
    }
}

__global__ void k_scan_add(int* __restrict__ out, const int* __restrict__ bsums, int n) {
    int i = blockIdx.x * blockDim.x + threadIdx.x;
    if (i < n) out[i] += bsums[i / SCAN_E];
}

// ================= CSR fill (src + norm packed) =================

__global__ void k_csr_fill(const int* __restrict__ src, const int* __restrict__ dst,
                           const float* __restrict__ dis, const int* __restrict__ rowptr,
                           int* __restrict__ cursor, int2* __restrict__ csr, int e) {
    int i = blockIdx.x * blockDim.x + threadIdx.x;
    if (i >= e) return;
    int s = src[i], d = dst[i];
    int p = rowptr[d] + atomicAdd(&cursor[d], 1);
    csr[p] = make_int2(s, __float_as_int(dis[s] * dis[d]));
}

// ================= gather-aggregate (raw 22-dim features, pre-GEMM) =================
// wave = 1 node; lane = (esub 0..1) * 32 + sub 0..31; 4 edges in flight (unroll 2)

__global__ void k_gather22(const float* __restrict__ X, const int* __restrict__ rowptr,
                           const int2* __restrict__ csr, const float* __restrict__ dinv,
                           float* __restrict__ out, int n) {
    int node = blockIdx.x * 4 + (threadIdx.x >> 6);
    if (node >= n) return;
    int lane = threadIdx.x & 63;
    int esub = lane >> 5;        // 0..1
    int sub  = lane & 31;        // 0..31
    bool act = sub < 22;
    int beg = rowptr[node], end = rowptr[node + 1];
    float acc0 = 0.0f, acc1 = 0.0f;
    for (int e = beg; e < end; e += 4) {
        int i0 = e + esub;
        int i1 = e + 2 + esub;
        int2 m0 = csr[min(i0, end - 1)];
        int2 m1 = csr[min(i1, end - 1)];
        float n0 = (i0 < end) ? __int_as_float(m0.y) : 0.0f;
        float n1 = (i1 < end) ? __int_as_float(m1.y) : 0.0f;
        if (act) {
            acc0 += X[(size_t)m0.x * 22 + sub] * n0;
            acc1 += X[(size_t)m1.x * 22 + sub] * n1;
        }
    }
    float acc = acc0 + acc1;
    acc += __shfl_xor(acc, 32);
    if (esub == 0 && sub < 24) {
        float val = act ? (acc + X[(size_t)node * 22 + sub] * dinv[node]) : 0.0f;
        out[(size_t)node * 24 + sub] = val;
    }
}

// 64-dim: wave = 1 node; lane = (esub 0..3)*16 + fchunk 0..15 (float4);
// 8 edges in flight per iteration (unroll 2)
__global__ void k_gather64(const float* __restrict__ H, const int* __restrict__ rowptr,
                           const int2* __restrict__ csr, const float* __restrict__ dinv,
                           float* __restrict__ out, int n) {
    int node = blockIdx.x * 4 + (threadIdx.x >> 6);
    if (node >= n) return;
    int lane = threadIdx.x & 63;
    int esub = lane >> 4;        // 0..3
    int fch  = lane & 15;        // 0..15
    const float4* H4 = (const float4*)H;
    int beg = rowptr[node], end = rowptr[node + 1];
    float4 a0 = make_float4(0, 0, 0, 0), a1 = a0;
    for (int e = beg; e < end; e += 8) {
        int i0 = e + esub;
        int i1 = e + 4 + esub;
        int2 m0 = csr[min(i0, end - 1)];
        int2 m1 = csr[min(i1, end - 1)];
        float n0 = (i0 < end) ? __int_as_float(m0.y) : 0.0f;
        float n1 = (i1 < end) ? __int_as_float(m1.y) : 0.0f;
        float4 h0 = H4[(size_t)m0.x * 16 + fch];
        float4 h1 = H4[(size_t)m1.x * 16 + fch];
        a0.x += h0.x * n0; a0.y += h0.y * n0; a0.z += h0.z * n0; a0.w += h0.w * n0;
        a1.x += h1.x * n1; a1.y += h1.y * n1; a1.z += h1.z * n1; a1.w += h1.w * n1;
    }
    float4 acc;
    acc.x = a0.x + a1.x; acc.y = a0.y + a1.y; acc.z = a0.z + a1.z; acc.w = a0.w + a1.w;
    acc.x += __shfl_xor(acc.x, 32); acc.y += __shfl_xor(acc.y, 32);
    acc.z += __shfl_xor(acc.z, 32); acc.w += __shfl_xor(acc.w, 32);
    acc.x += __shfl_xor(acc.x, 16); acc.y += __shfl_xor(acc.y, 16);
    acc.z += __shfl_xor(acc.z, 16); acc.w += __shfl_xor(acc.w, 16);
    if (esub == 0) {
        float di = dinv[node];
        float4 hs = H4[(size_t)node * 16 + fch];
        float4 r;
        r.x = acc.x + hs.x * di;
        r.y = acc.y + hs.y * di;
        r.z = acc.z + hs.z * di;
        r.w = acc.w + hs.w * di;
        ((float4*)out)[(size_t)node * 16 + fch] = r;
    }
}

// ================= fused GEMM + bias + BN + ReLU =================

template <int FIN_PAD, int FOUT, bool HAS_BN>
__global__ void k_gemm_fused(const float* __restrict__ P, const float* __restrict__ W,
                             int fin_real, const float* __restrict__ b,
                             const float* __restrict__ g, const float* __restrict__ be,
                             const float* __restrict__ m, const float* __restrict__ v,
                             float* __restrict__ out, int n) {
    __shared__ float Ws[FIN_PAD * FOUT];
    __shared__ float Af[FOUT], Cf[FOUT];
    for (int i = threadIdx.x; i < FIN_PAD * FOUT; i += 256) {
        int r = i / FOUT, c = i % FOUT;
        Ws[i] = (r < fin_real) ? W[r * FOUT + c] : 0.0f;
    }
    for (int f = threadIdx.x; f < FOUT; f += 256) {
        float A = HAS_BN ? g[f] * rsqrtf(v[f] + BN_EPS) : 1.0f;
        Af[f] = A;
        Cf[f] = HAS_BN ? be[f] + (b[f] - m[f]) * A : b[f];
    }
    __syncthreads();
    int node = blockIdx.x * 256 + threadIdx.x;
    if (node >= n) return;

    float4 xr[FIN_PAD / 4];
    const float4* p4 = (const float4*)(P + (size_t)node * FIN_PAD);
#pragma unroll
    for (int i = 0; i < FIN_PAD / 4; ++i) xr[i] = p4[i];
    const float* x = (const float*)xr;

    float4* o4 = (float4*)(out + (size_t)node * FOUT);
    for (int c0 = 0; c0 < FOUT; c0 += 16) {
        float4 acc0 = make_float4(0, 0, 0, 0), acc1 = acc0, acc2 = acc0, acc3 = acc0;
#pragma unroll
        for (int k = 0; k < FIN_PAD; ++k) {
            float xv = x[k];
            const float4* wr = (const float4*)(Ws + k * FOUT + c0);
            float4 w0 = wr[0], w1 = wr[1], w2 = wr[2], w3 = wr[3];
            acc0.x += xv * w0.x; acc0.y += xv * w0.y; acc0.z += xv * w0.z; acc0.w += xv * w0.w;
            acc1.x += xv * w1.x; acc1.y += xv * w1.y; acc1.z += xv * w1.z; acc1.w += xv * w1.w;
            acc2.x += xv * w2.x; acc2.y += xv * w2.y; acc2.z += xv * w2.z; acc2.w += xv * w2.w;
            acc3.x += xv * w3.x; acc3.y += xv * w3.y; acc3.z += xv * w3.z; acc3.w += xv * w3.w;
        }
        float4 accs[4] = {acc0, acc1, acc2, acc3};
#pragma unroll
        for (int j = 0; j < 4; ++j) {
            int f = c0 + j * 4;
            float4 r;
            r.x = fmaxf(accs[j].x * Af[f + 0] + Cf[f + 0], 0.0f);
            r.y = fmaxf(accs[j].y * Af[f + 1] + Cf[f + 1], 0.0f);
            r.z = fmaxf(accs[j].z * Af[f + 2] + Cf[f + 2], 0.0f);
            r.w = fmaxf(accs[j].w * Af[f + 3] + Cf[f + 3], 0.0f);
            o4[(c0 / 4) + j] = r;
        }
    }
}

// ================= pool =================

__global__ void k_pool(const float* __restrict__ H, const int* __restrict__ batch,
                       float* __restrict__ sums, int n) {
    int f = threadIdx.x;            // 0..127
    int base = blockIdx.x * 32;
    if (base >= n) return;
    int endn = min(base + 32, n);
    int cur = batch[base];
    float acc = 0.0f;
    for (int node = base; node < endn; ++node) {
        int bb = batch[node];
        if (bb != cur) { atomicAdd(&sums[cur * 128 + f], acc); acc = 0.0f; cur = bb; }
        acc += H[(size_t)node * 128 + f];
    }
    atomicAdd(&sums[cur * 128 + f], acc);
}

// batch is sorted: counts via binary search, no atomics
__global__ void k_cnt_bs(const int* __restrict__ batch, float* __restrict__ cnt,
                         int n, int nB) {
    int b = blockIdx.x * blockDim.x + threadIdx.x;
    if (b >= nB) return;
    int lo = 0, hi = n;
    while (lo < hi) { int mid = (lo + hi) >> 1; if (batch[mid] < b) lo = mid + 1; else hi = mid; }
    int start = lo;
    lo = 0; hi = n;
    while (lo < hi) { int mid = (lo + hi) >> 1; if (batch[mid] < b + 1) lo = mid + 1; else hi = mid; }
    cnt[b] = (float)(lo - start);
}

__global__ void k_pool_div(const float* __restrict__ sums, const float* __restrict__ cnt,
                           float* __restrict__ out, int nB) {
    int i = blockIdx.x * blockDim.x + threadIdx.x;
    if (i < nB * 128) out[i] = sums[i] / fmaxf(cnt[i >> 7], 1.0f);
}

// ================= launch =================

extern "C" void kernel_launch(void* const* d_in, const int* in_sizes, int n_in,
                              void* d_out, int out_size, void* d_ws, size_t ws_size,
                              hipStream_t stream) {
    const float* x   = (const float*)d_in[0];
    const int*   ei  = (const int*)d_in[1];
    const int*   bat = (const int*)d_in[2];
    const float* W1  = (const float*)d_in[3];
    const float* b1  = (const float*)d_in[4];
    const float* W2  = (const float*)d_in[5];
    const float* b2  = (const float*)d_in[6];
    const float* W3  = (const float*)d_in[7];
    const float* b3  = (const float*)d_in[8];
    const float* g1  = (const float*)d_in[9];
    const float* be1 = (const float*)d_in[10];
    const float* m1  = (const float*)d_in[11];
    const float* v1  = (const float*)d_in[12];
    const float* g2  = (const float*)d_in[13];
    const float* be2 = (const float*)d_in[14];
    const float* m2  = (const float*)d_in[15];
    const float* v2  = (const float*)d_in[16];

    const int N = in_sizes[0] / 22;
    const int E = in_sizes[1] / 2;
    const int B = out_size / 128;
    const int* src = ei;
    const int* dst = ei + E;

    size_t off = 0;
    char* base = (char*)d_ws;
    auto alloc = [&](size_t bytes) -> void* {
        void* p = base + off;
        off = (off + bytes + 255) & ~(size_t)255;
        return p;
    };
    int*   deg    = (int*)alloc((size_t)N * 4);
    int*   rowptr = (int*)alloc((size_t)(N + 1) * 4);
    int*   cursor = (int*)alloc((size_t)N * 4);
    int*   bsums  = (int*)alloc(512);
    float* dis    = (float*)alloc((size_t)N * 4);
    float* dinv   = (float*)alloc((size_t)N * 4);
    int2*  csr    = (int2*)alloc((size_t)E * 8);
    float* bufA   = (float*)alloc((size_t)N * 128 * 4);
    float* bufB   = (float*)alloc((size_t)N * 128 * 4);
    float* sums   = (float*)alloc((size_t)B * 128 * 4 + (size_t)B * 4);
    float* cnt    = sums + (size_t)B * 128;

    const int T = 256;
    auto blk = [](long long n, int t) { return (int)((n + t - 1) / t); };

    // ---- CSR build ----
    hipMemsetAsync(deg, 0, (size_t)N * 4, stream);
    k_hist<<<blk(E, T), T, 0, stream>>>(dst, deg, E);
    k_deg_fin<<<blk(N, T), T, 0, stream>>>(deg, dis, dinv, N);
    int nb = (N + SCAN_E - 1) / SCAN_E;
    k_scan_block<<<nb, SCAN_T, 0, stream>>>(deg, rowptr, bsums, N);
    k_scan_carry<<<1, 64, 0, stream>>>(bsums, nb, rowptr, N);
    k_scan_add<<<blk(N, T), T, 0, stream>>>(rowptr, bsums, N);
    hipMemsetAsync(cursor, 0, (size_t)N * 4, stream);
    k_csr_fill<<<blk(E, T), T, 0, stream>>>(src, dst, dis, rowptr, cursor, csr, E);

    // ---- layer 1: agg(X) [N x 24 padded] -> gemm 22->64 + BN1 + ReLU ----
    k_gather22<<<blk(N, 4), T, 0, stream>>>(x, rowptr, csr, dinv, bufA, N);
    k_gemm_fused<24, 64, true><<<blk(N, T), T, 0, stream>>>(
        bufA, W1, 22, b1, g1, be1, m1, v1, bufB, N);

    // ---- layer 2: agg(h1) -> gemm 64->64 + BN2 + ReLU ----
    k_gather64<<<blk(N, 4), T, 0, stream>>>(bufB, rowptr, csr, dinv, bufA, N);
    k_gemm_fused<64, 64, true><<<blk(N, T), T, 0, stream>>>(
        bufA, W2, 64, b2, g2, be2, m2, v2, bufB, N);

    // ---- layer 3: agg(h2) -> gemm 64->128 + ReLU ----
    k_gather64<<<blk(N, 4), T, 0, stream>>>(bufB, rowptr, csr, dinv, bufA, N);
    k_gemm_fused<64, 128, false><<<blk(N, T), T, 0, stream>>>(
        bufA, W3, 64, b3, nullptr, nullptr, nullptr, nullptr, bufB, N);

    // ---- global mean pool ----
    hipMemsetAsync(sums, 0, (size_t)B * 128 * sizeof(float), stream);
    k_pool<<<blk(N, 32), 128, 0, stream>>>(bufB, bat, sums, N);
    k_cnt_bs<<<1, 256, 0, stream>>>(bat, cnt, N, B);
    k_pool_div<<<blk(B * 128, T), T, 0, stream>>>(sums, cnt, (float*)d_out, B);
}

// Round 6
// 557.712 us; speedup vs baseline: 11.2055x; 1.0626x over previous
//
#include <hip/hip_runtime.h>

#define BN_EPS 1e-5f

// ================= degree histogram / norms =================

__global__ void k_hist(const int* __restrict__ dst, int* __restrict__ deg, int e) {
    int i = blockIdx.x * blockDim.x + threadIdx.x;
    if (i < e) atomicAdd(&deg[dst[i]], 1);
}

__global__ void k_deg_fin(const int* __restrict__ deg, float* __restrict__ dis,
                          float* __restrict__ dinv, int n) {
    int i = blockIdx.x * blockDim.x + threadIdx.x;
    if (i < n) {
        float d = (float)(deg[i] + 1);   // + self-loop
        dis[i]  = rsqrtf(d);
        dinv[i] = 1.0f / d;
    }
}

// ================= exclusive scan (rowptr) =================

#define SCAN_T 256
#define SCAN_E 1024

__global__ void k_scan_block(const int* __restrict__ in, int* __restrict__ out,
                             int* __restrict__ bsums, int n) {
    __shared__ int lds[SCAN_T];
    int t = threadIdx.x;
    int base = blockIdx.x * SCAN_E + t * 4;
    int v[4];
#pragma unroll
    for (int j = 0; j < 4; ++j) { int idx = base + j; v[j] = (idx < n) ? in[idx] : 0; }
    int s0 = v[0] + v[1] + v[2] + v[3];
    int val = s0;
    lds[t] = val;
    __syncthreads();
    for (int off = 1; off < SCAN_T; off <<= 1) {
        int tmp = (t >= off) ? lds[t - off] : 0;
        __syncthreads();
        val += tmp;
        lds[t] = val;
        __syncthreads();
    }
    int run = val - s0;
#pragma unroll
    for (int j = 0; j < 4; ++j) { int idx = base + j; if (idx < n) out[idx] = run; run += v[j]; }
    if (t == SCAN_T - 1) bsums[blockIdx.x] = val;
}

__global__ void k_scan_carry(int* __restrict__ bsums, int nb, int* __restrict__ rowptr, int n) {
    if (threadIdx.x == 0 && blockIdx.x == 0) {
        int run = 0;
        for (int i = 0; i < nb; ++i) { int t = bsums[i]; bsums[i] = run; run += t; }
        rowptr[n] = run;
    }
}

__global__ void k_scan_add(int* __restrict__ out, const int* __restrict__ bsums, int n) {
    int i = blockIdx.x * blockDim.x + threadIdx.x;
    if (i < n) out[i] += bsums[i / SCAN_E];
}

// ================= CSR fill (src + norm packed) =================

__global__ void k_csr_fill(const int* __restrict__ src, const int* __restrict__ dst,
                           const float* __restrict__ dis, const int* __restrict__ rowptr,
                           int* __restrict__ cursor, int2* __restrict__ csr, int e) {
    int i = blockIdx.x * blockDim.x + threadIdx.x;
    if (i >= e) return;
    int s = src[i], d = dst[i];
    int p = rowptr[d] + atomicAdd(&cursor[d], 1);
    csr[p] = make_int2(s, __float_as_int(dis[s] * dis[d]));
}

// ================= gather-aggregate =================

__global__ void k_gather22(const float* __restrict__ X, const int* __restrict__ rowptr,
                           const int2* __restrict__ csr, const float* __restrict__ dinv,
                           float* __restrict__ out, int n) {
    int node = blockIdx.x * 4 + (threadIdx.x >> 6);
    if (node >= n) return;
    int lane = threadIdx.x & 63;
    int esub = lane >> 5;        // 0..1
    int sub  = lane & 31;        // 0..31
    bool act = sub < 22;
    int beg = rowptr[node], end = rowptr[node + 1];
    float acc0 = 0.0f, acc1 = 0.0f;
    for (int e = beg; e < end; e += 4) {
        int i0 = e + esub;
        int i1 = e + 2 + esub;
        int2 m0 = csr[min(i0, end - 1)];
        int2 m1 = csr[min(i1, end - 1)];
        float n0 = (i0 < end) ? __int_as_float(m0.y) : 0.0f;
        float n1 = (i1 < end) ? __int_as_float(m1.y) : 0.0f;
        if (act) {
            acc0 += X[(size_t)m0.x * 22 + sub] * n0;
            acc1 += X[(size_t)m1.x * 22 + sub] * n1;
        }
    }
    float acc = acc0 + acc1;
    acc += __shfl_xor(acc, 32);
    if (esub == 0 && sub < 24) {
        float val = act ? (acc + X[(size_t)node * 22 + sub] * dinv[node]) : 0.0f;
        out[(size_t)node * 24 + sub] = val;
    }
}

__global__ void k_gather64(const float* __restrict__ H, const int* __restrict__ rowptr,
                           const int2* __restrict__ csr, const float* __restrict__ dinv,
                           float* __restrict__ out, int n) {
    int node = blockIdx.x * 4 + (threadIdx.x >> 6);
    if (node >= n) return;
    int lane = threadIdx.x & 63;
    int esub = lane >> 4;        // 0..3
    int fch  = lane & 15;        // 0..15
    const float4* H4 = (const float4*)H;
    int beg = rowptr[node], end = rowptr[node + 1];
    float4 a0 = make_float4(0, 0, 0, 0), a1 = a0;
    for (int e = beg; e < end; e += 8) {
        int i0 = e + esub;
        int i1 = e + 4 + esub;
        int2 m0 = csr[min(i0, end - 1)];
        int2 m1 = csr[min(i1, end - 1)];
        float n0 = (i0 < end) ? __int_as_float(m0.y) : 0.0f;
        float n1 = (i1 < end) ? __int_as_float(m1.y) : 0.0f;
        float4 h0 = H4[(size_t)m0.x * 16 + fch];
        float4 h1 = H4[(size_t)m1.x * 16 + fch];
        a0.x += h0.x * n0; a0.y += h0.y * n0; a0.z += h0.z * n0; a0.w += h0.w * n0;
        a1.x += h1.x * n1; a1.y += h1.y * n1; a1.z += h1.z * n1; a1.w += h1.w * n1;
    }
    float4 acc;
    acc.x = a0.x + a1.x; acc.y = a0.y + a1.y; acc.z = a0.z + a1.z; acc.w = a0.w + a1.w;
    acc.x += __shfl_xor(acc.x, 32); acc.y += __shfl_xor(acc.y, 32);
    acc.z += __shfl_xor(acc.z, 32); acc.w += __shfl_xor(acc.w, 32);
    acc.x += __shfl_xor(acc.x, 16); acc.y += __shfl_xor(acc.y, 16);
    acc.z += __shfl_xor(acc.z, 16); acc.w += __shfl_xor(acc.w, 16);
    if (esub == 0) {
        float di = dinv[node];
        float4 hs = H4[(size_t)node * 16 + fch];
        float4 r;
        r.x = acc.x + hs.x * di;
        r.y = acc.y + hs.y * di;
        r.z = acc.z + hs.z * di;
        r.w = acc.w + hs.w * di;
        ((float4*)out)[(size_t)node * 16 + fch] = r;
    }
}

// ================= weight prep: Wp = W * A (zero-padded), Cf = be + (b-m)*A =================

template <int FIN_PAD, int FOUT, bool HAS_BN>
__global__ void k_prep(const float* __restrict__ W, int fin_real,
                       const float* __restrict__ b, const float* __restrict__ g,
                       const float* __restrict__ be, const float* __restrict__ m,
                       const float* __restrict__ v,
                       float* __restrict__ Wp, float* __restrict__ Cf) {
    int i = blockIdx.x * blockDim.x + threadIdx.x;
    if (i < FOUT) {
        float A = HAS_BN ? g[i] * rsqrtf(v[i] + BN_EPS) : 1.0f;
        Cf[i] = HAS_BN ? be[i] + (b[i] - m[i]) * A : b[i];
    }
    if (i < FIN_PAD * FOUT) {
        int r = i / FOUT, c = i % FOUT;
        float A = HAS_BN ? g[c] * rsqrtf(v[c] + BN_EPS) : 1.0f;
        Wp[i] = (r < fin_real) ? W[r * FOUT + c] * A : 0.0f;
    }
}

// ================= GEMM + epilogue: out = ReLU(P @ Wp + Cf) =================
// one node per thread; X row in VGPRs; W reads are wave-uniform -> scalar loads.

template <int FIN, int FOUT>
__global__ __launch_bounds__(256) void k_gemm2(const float* __restrict__ P,
                                               const float* __restrict__ Wp,
                                               const float* __restrict__ Cf,
                                               float* __restrict__ out, int n) {
    int node = blockIdx.x * 256 + threadIdx.x;
    if (node >= n) return;

    float4 xr[FIN / 4];
    const float4* p4 = (const float4*)(P + (size_t)node * FIN);
#pragma unroll
    for (int i = 0; i < FIN / 4; ++i) xr[i] = p4[i];
    const float* x = (const float*)xr;

    float4* o4 = (float4*)(out + (size_t)node * FOUT);
#pragma unroll 1
    for (int c0 = 0; c0 < FOUT; c0 += 16) {
        float4 a0 = make_float4(0, 0, 0, 0), a1 = a0, a2 = a0, a3 = a0;
        const float* wbase = Wp + c0;
#pragma unroll
        for (int k = 0; k < FIN; ++k) {
            float xv = x[k];
            const float4* wr = (const float4*)(wbase + k * FOUT);
            float4 w0 = wr[0], w1 = wr[1], w2 = wr[2], w3 = wr[3];
            a0.x = fmaf(xv, w0.x, a0.x); a0.y = fmaf(xv, w0.y, a0.y);
            a0.z = fmaf(xv, w0.z, a0.z); a0.w = fmaf(xv, w0.w, a0.w);
            a1.x = fmaf(xv, w1.x, a1.x); a1.y = fmaf(xv, w1.y, a1.y);
            a1.z = fmaf(xv, w1.z, a1.z); a1.w = fmaf(xv, w1.w, a1.w);
            a2.x = fmaf(xv, w2.x, a2.x); a2.y = fmaf(xv, w2.y, a2.y);
            a2.z = fmaf(xv, w2.z, a2.z); a2.w = fmaf(xv, w2.w, a2.w);
            a3.x = fmaf(xv, w3.x, a3.x); a3.y = fmaf(xv, w3.y, a3.y);
            a3.z = fmaf(xv, w3.z, a3.z); a3.w = fmaf(xv, w3.w, a3.w);
        }
        const float4* c4 = (const float4*)(Cf + c0);
        float4 cA = c4[0], cB = c4[1], cC = c4[2], cD = c4[3];
        float4 r0, r1, r2, r3;
        r0.x = fmaxf(a0.x + cA.x, 0.0f); r0.y = fmaxf(a0.y + cA.y, 0.0f);
        r0.z = fmaxf(a0.z + cA.z, 0.0f); r0.w = fmaxf(a0.w + cA.w, 0.0f);
        r1.x = fmaxf(a1.x + cB.x, 0.0f); r1.y = fmaxf(a1.y + cB.y, 0.0f);
        r1.z = fmaxf(a1.z + cB.z, 0.0f); r1.w = fmaxf(a1.w + cB.w, 0.0f);
        r2.x = fmaxf(a2.x + cC.x, 0.0f); r2.y = fmaxf(a2.y + cC.y, 0.0f);
        r2.z = fmaxf(a2.z + cC.z, 0.0f); r2.w = fmaxf(a2.w + cC.w, 0.0f);
        r3.x = fmaxf(a3.x + cD.x, 0.0f); r3.y = fmaxf(a3.y + cD.y, 0.0f);
        r3.z = fmaxf(a3.z + cD.z, 0.0f); r3.w = fmaxf(a3.w + cD.w, 0.0f);
        o4[(c0 >> 2) + 0] = r0;
        o4[(c0 >> 2) + 1] = r1;
        o4[(c0 >> 2) + 2] = r2;
        o4[(c0 >> 2) + 3] = r3;
    }
}

// ================= pool =================

__global__ void k_pool(const float* __restrict__ H, const int* __restrict__ batch,
                       float* __restrict__ sums, int n) {
    int f = threadIdx.x;            // 0..127
    int base = blockIdx.x * 32;
    if (base >= n) return;
    int endn = min(base + 32, n);
    int cur = batch[base];
    float acc = 0.0f;
    for (int node = base; node < endn; ++node) {
        int bb = batch[node];
        if (bb != cur) { atomicAdd(&sums[cur * 128 + f], acc); acc = 0.0f; cur = bb; }
        acc += H[(size_t)node * 128 + f];
    }
    atomicAdd(&sums[cur * 128 + f], acc);
}

__global__ void k_cnt_bs(const int* __restrict__ batch, float* __restrict__ cnt,
                         int n, int nB) {
    int b = blockIdx.x * blockDim.x + threadIdx.x;
    if (b >= nB) return;
    int lo = 0, hi = n;
    while (lo < hi) { int mid = (lo + hi) >> 1; if (batch[mid] < b) lo = mid + 1; else hi = mid; }
    int start = lo;
    lo = 0; hi = n;
    while (lo < hi) { int mid = (lo + hi) >> 1; if (batch[mid] < b + 1) lo = mid + 1; else hi = mid; }
    cnt[b] = (float)(lo - start);
}

__global__ void k_pool_div(const float* __restrict__ sums, const float* __restrict__ cnt,
                           float* __restrict__ out, int nB) {
    int i = blockIdx.x * blockDim.x + threadIdx.x;
    if (i < nB * 128) out[i] = sums[i] / fmaxf(cnt[i >> 7], 1.0f);
}

// ================= launch =================

extern "C" void kernel_launch(void* const* d_in, const int* in_sizes, int n_in,
                              void* d_out, int out_size, void* d_ws, size_t ws_size,
                              hipStream_t stream) {
    const float* x   = (const float*)d_in[0];
    const int*   ei  = (const int*)d_in[1];
    const int*   bat = (const int*)d_in[2];
    const float* W1  = (const float*)d_in[3];
    const float* b1  = (const float*)d_in[4];
    const float* W2  = (const float*)d_in[5];
    const float* b2  = (const float*)d_in[6];
    const float* W3  = (const float*)d_in[7];
    const float* b3  = (const float*)d_in[8];
    const float* g1  = (const float*)d_in[9];
    const float* be1 = (const float*)d_in[10];
    const float* m1  = (const float*)d_in[11];
    const float* v1  = (const float*)d_in[12];
    const float* g2  = (const float*)d_in[13];
    const float* be2 = (const float*)d_in[14];
    const float* m2  = (const float*)d_in[15];
    const float* v2  = (const float*)d_in[16];

    const int N = in_sizes[0] / 22;
    const int E = in_sizes[1] / 2;
    const int B = out_size / 128;
    const int* src = ei;
    const int* dst = ei + E;

    size_t off = 0;
    char* base = (char*)d_ws;
    auto alloc = [&](size_t bytes) -> void* {
        void* p = base + off;
        off = (off + bytes + 255) & ~(size_t)255;
        return p;
    };
    int*   deg    = (int*)alloc((size_t)N * 4);
    int*   rowptr = (int*)alloc((size_t)(N + 1) * 4);
    int*   cursor = (int*)alloc((size_t)N * 4);
    int*   bsums  = (int*)alloc(512);
    float* dis    = (float*)alloc((size_t)N * 4);
    float* dinv   = (float*)alloc((size_t)N * 4);
    int2*  csr    = (int2*)alloc((size_t)E * 8);
    float* bufA   = (float*)alloc((size_t)N * 128 * 4);
    float* bufB   = (float*)alloc((size_t)N * 128 * 4);
    float* sums   = (float*)alloc((size_t)B * 128 * 4 + (size_t)B * 4);
    float* cnt    = sums + (size_t)B * 128;
    float* Wp1    = (float*)alloc(24 * 64 * 4);
    float* Wp2    = (float*)alloc(64 * 64 * 4);
    float* Wp3    = (float*)alloc(64 * 128 * 4);
    float* C1     = (float*)alloc(64 * 4);
    float* C2     = (float*)alloc(64 * 4);
    float* C3     = (float*)alloc(128 * 4);

    const int T = 256;
    auto blk = [](long long n, int t) { return (int)((n + t - 1) / t); };

    // ---- weight prep (fold BN scale into W, pad layer-1 W to 24 rows) ----
    k_prep<24, 64, true ><<<blk(24 * 64, T), T, 0, stream>>>(W1, 22, b1, g1, be1, m1, v1, Wp1, C1);
    k_prep<64, 64, true ><<<blk(64 * 64, T), T, 0, stream>>>(W2, 64, b2, g2, be2, m2, v2, Wp2, C2);
    k_prep<64, 128, false><<<blk(64 * 128, T), T, 0, stream>>>(W3, 64, b3, nullptr, nullptr, nullptr, nullptr, Wp3, C3);

    // ---- CSR build ----
    hipMemsetAsync(deg, 0, (size_t)N * 4, stream);
    k_hist<<<blk(E, T), T, 0, stream>>>(dst, deg, E);
    k_deg_fin<<<blk(N, T), T, 0, stream>>>(deg, dis, dinv, N);
    int nb = (N + SCAN_E - 1) / SCAN_E;
    k_scan_block<<<nb, SCAN_T, 0, stream>>>(deg, rowptr, bsums, N);
    k_scan_carry<<<1, 64, 0, stream>>>(bsums, nb, rowptr, N);
    k_scan_add<<<blk(N, T), T, 0, stream>>>(rowptr, bsums, N);
    hipMemsetAsync(cursor, 0, (size_t)N * 4, stream);
    k_csr_fill<<<blk(E, T), T, 0, stream>>>(src, dst, dis, rowptr, cursor, csr, E);

    // ---- layer 1: agg(X) [N x 24 padded] -> gemm 24->64 (+BN folded) ----
    k_gather22<<<blk(N, 4), T, 0, stream>>>(x, rowptr, csr, dinv, bufA, N);
    k_gemm2<24, 64><<<blk(N, T), T, 0, stream>>>(bufA, Wp1, C1, bufB, N);

    // ---- layer 2: agg(h1) -> gemm 64->64 (+BN folded) ----
    k_gather64<<<blk(N, 4), T, 0, stream>>>(bufB, rowptr, csr, dinv, bufA, N);
    k_gemm2<64, 64><<<blk(N, T), T, 0, stream>>>(bufA, Wp2, C2, bufB, N);

    // ---- layer 3: agg(h2) -> gemm 64->128 ----
    k_gather64<<<blk(N, 4), T, 0, stream>>>(bufB, rowptr, csr, dinv, bufA, N);
    k_gemm2<64, 128><<<blk(N, T), T, 0, stream>>>(bufA, Wp3, C3, bufB, N);

    // ---- global mean pool ----
    hipMemsetAsync(sums, 0, (size_t)B * 128 * sizeof(float), stream);
    k_pool<<<blk(N, 32), 128, 0, stream>>>(bufB, bat, sums, N);
    k_cnt_bs<<<1, 256, 0, stream>>>(bat, cnt, N, B);
    k_pool_div<<<blk(B * 128, T), T, 0, stream>>>(sums, cnt, (float*)d_out, B);
}

// Round 7
// 535.985 us; speedup vs baseline: 11.6597x; 1.0405x over previous
//
#include <hip/hip_runtime.h>

#define BN_EPS 1e-5f

// ================= degree histogram + rank (atomic returns old = rank within dst) =================

__global__ void k_hist_rank(const int* __restrict__ dst, int* __restrict__ deg,
                            int* __restrict__ rank, int e) {
    int i = blockIdx.x * blockDim.x + threadIdx.x;
    if (i < e) rank[i] = atomicAdd(&deg[dst[i]], 1);
}

__global__ void k_deg_fin(const int* __restrict__ deg, float* __restrict__ dis,
                          float* __restrict__ dinv, int n) {
    int i = blockIdx.x * blockDim.x + threadIdx.x;
    if (i < n) {
        float d = (float)(deg[i] + 1);   // + self-loop
        dis[i]  = rsqrtf(d);
        dinv[i] = 1.0f / d;
    }
}

// ================= exclusive scan (rowptr) =================

#define SCAN_T 256
#define SCAN_E 1024

__global__ void k_scan_block(const int* __restrict__ in, int* __restrict__ out,
                             int* __restrict__ bsums, int n) {
    __shared__ int lds[SCAN_T];
    int t = threadIdx.x;
    int base = blockIdx.x * SCAN_E + t * 4;
    int v[4];
#pragma unroll
    for (int j = 0; j < 4; ++j) { int idx = base + j; v[j] = (idx < n) ? in[idx] : 0; }
    int s0 = v[0] + v[1] + v[2] + v[3];
    int val = s0;
    lds[t] = val;
    __syncthreads();
    for (int off = 1; off < SCAN_T; off <<= 1) {
        int tmp = (t >= off) ? lds[t - off] : 0;
        __syncthreads();
        val += tmp;
        lds[t] = val;
        __syncthreads();
    }
    int run = val - s0;
#pragma unroll
    for (int j = 0; j < 4; ++j) { int idx = base + j; if (idx < n) out[idx] = run; run += v[j]; }
    if (t == SCAN_T - 1) bsums[blockIdx.x] = val;
}

__global__ void k_scan_carry(int* __restrict__ bsums, int nb, int* __restrict__ rowptr, int n) {
    if (threadIdx.x == 0 && blockIdx.x == 0) {
        int run = 0;
        for (int i = 0; i < nb; ++i) { int t = bsums[i]; bsums[i] = run; run += t; }
        rowptr[n] = run;
    }
}

__global__ void k_scan_add(int* __restrict__ out, const int* __restrict__ bsums, int n) {
    int i = blockIdx.x * blockDim.x + threadIdx.x;
    if (i < n) out[i] += bsums[i / SCAN_E];
}

// ================= CSR fill — atomic-free scatter using rank =================

__global__ void k_csr_fill(const int* __restrict__ src, const int* __restrict__ dst,
                           const int* __restrict__ rank, const float* __restrict__ dis,
                           const int* __restrict__ rowptr, int2* __restrict__ csr, int e) {
    int i = blockIdx.x * blockDim.x + threadIdx.x;
    if (i >= e) return;
    int s = src[i], d = dst[i];
    int p = rowptr[d] + rank[i];
    csr[p] = make_int2(s, __float_as_int(dis[s] * dis[d]));
}

// ================= gather-aggregate =================
// 22-dim: wave = node; lane = esub(2) x sub(32); 8 edges in flight (4 chains)

__global__ void k_gather22(const float* __restrict__ X, const int* __restrict__ rowptr,
                           const int2* __restrict__ csr, const float* __restrict__ dinv,
                           float* __restrict__ out, int n) {
    int node = blockIdx.x * 4 + (threadIdx.x >> 6);
    if (node >= n) return;
    int lane = threadIdx.x & 63;
    int esub = lane >> 5;        // 0..1
    int sub  = lane & 31;        // 0..31
    bool act = sub < 22;
    int beg = rowptr[node], end = rowptr[node + 1];
    float acc0 = 0.0f, acc1 = 0.0f, acc2 = 0.0f, acc3 = 0.0f;
    for (int e = beg; e < end; e += 8) {
        int i0 = e + esub, i1 = e + 2 + esub, i2 = e + 4 + esub, i3 = e + 6 + esub;
        int2 m0 = csr[min(i0, end - 1)];
        int2 m1 = csr[min(i1, end - 1)];
        int2 m2 = csr[min(i2, end - 1)];
        int2 m3 = csr[min(i3, end - 1)];
        if (act && i0 < end) acc0 += X[(size_t)m0.x * 22 + sub] * __int_as_float(m0.y);
        if (act && i1 < end) acc1 += X[(size_t)m1.x * 22 + sub] * __int_as_float(m1.y);
        if (act && i2 < end) acc2 += X[(size_t)m2.x * 22 + sub] * __int_as_float(m2.y);
        if (act && i3 < end) acc3 += X[(size_t)m3.x * 22 + sub] * __int_as_float(m3.y);
    }
    float acc = (acc0 + acc1) + (acc2 + acc3);
    acc += __shfl_xor(acc, 32);
    if (esub == 0 && sub < 24) {
        float val = act ? (acc + X[(size_t)node * 22 + sub] * dinv[node]) : 0.0f;
        out[(size_t)node * 24 + sub] = val;
    }
}

// 64-dim: wave = node; lane = esub(4) x fch(16); 16 edges in flight (4 chains)
__global__ void k_gather64(const float* __restrict__ H, const int* __restrict__ rowptr,
                           const int2* __restrict__ csr, const float* __restrict__ dinv,
                           float* __restrict__ out, int n) {
    int node = blockIdx.x * 4 + (threadIdx.x >> 6);
    if (node >= n) return;
    int lane = threadIdx.x & 63;
    int esub = lane >> 4;        // 0..3
    int fch  = lane & 15;        // 0..15
    const float4* H4 = (const float4*)H;
    int beg = rowptr[node], end = rowptr[node + 1];
    float4 a0 = make_float4(0, 0, 0, 0), a1 = a0, a2 = a0, a3 = a0;
    for (int e = beg; e < end; e += 16) {
        int i0 = e + esub, i1 = e + 4 + esub, i2 = e + 8 + esub, i3 = e + 12 + esub;
        int2 m0 = csr[min(i0, end - 1)];
        int2 m1 = csr[min(i1, end - 1)];
        int2 m2 = csr[min(i2, end - 1)];
        int2 m3 = csr[min(i3, end - 1)];
        if (i0 < end) {
            float nn = __int_as_float(m0.y);
            float4 h = H4[(size_t)m0.x * 16 + fch];
            a0.x = fmaf(h.x, nn, a0.x); a0.y = fmaf(h.y, nn, a0.y);
            a0.z = fmaf(h.z, nn, a0.z); a0.w = fmaf(h.w, nn, a0.w);
        }
        if (i1 < end) {
            float nn = __int_as_float(m1.y);
            float4 h = H4[(size_t)m1.x * 16 + fch];
            a1.x = fmaf(h.x, nn, a1.x); a1.y = fmaf(h.y, nn, a1.y);
            a1.z = fmaf(h.z, nn, a1.z); a1.w = fmaf(h.w, nn, a1.w);
        }
        if (i2 < end) {
            float nn = __int_as_float(m2.y);
            float4 h = H4[(size_t)m2.x * 16 + fch];
            a2.x = fmaf(h.x, nn, a2.x); a2.y = fmaf(h.y, nn, a2.y);
            a2.z = fmaf(h.z, nn, a2.z); a2.w = fmaf(h.w, nn, a2.w);
        }
        if (i3 < end) {
            float nn = __int_as_float(m3.y);
            float4 h = H4[(size_t)m3.x * 16 + fch];
            a3.x = fmaf(h.x, nn, a3.x); a3.y = fmaf(h.y, nn, a3.y);
            a3.z = fmaf(h.z, nn, a3.z); a3.w = fmaf(h.w, nn, a3.w);
        }
    }
    float4 acc;
    acc.x = (a0.x + a1.x) + (a2.x + a3.x);
    acc.y = (a0.y + a1.y) + (a2.y + a3.y);
    acc.z = (a0.z + a1.z) + (a2.z + a3.z);
    acc.w = (a0.w + a1.w) + (a2.w + a3.w);
    acc.x += __shfl_xor(acc.x, 32); acc.y += __shfl_xor(acc.y, 32);
    acc.z += __shfl_xor(acc.z, 32); acc.w += __shfl_xor(acc.w, 32);
    acc.x += __shfl_xor(acc.x, 16); acc.y += __shfl_xor(acc.y, 16);
    acc.z += __shfl_xor(acc.z, 16); acc.w += __shfl_xor(acc.w, 16);
    if (esub == 0) {
        float di = dinv[node];
        float4 hs = H4[(size_t)node * 16 + fch];
        float4 r;
        r.x = fmaf(hs.x, di, acc.x);
        r.y = fmaf(hs.y, di, acc.y);
        r.z = fmaf(hs.z, di, acc.z);
        r.w = fmaf(hs.w, di, acc.w);
        ((float4*)out)[(size_t)node * 16 + fch] = r;
    }
}

// ================= weight prep: Wp = W * A (zero-padded), Cf = be + (b-m)*A =================

template <int FIN_PAD, int FOUT, bool HAS_BN>
__global__ void k_prep(const float* __restrict__ W, int fin_real,
                       const float* __restrict__ b, const float* __restrict__ g,
                       const float* __restrict__ be, const float* __restrict__ m,
                       const float* __restrict__ v,
                       float* __restrict__ Wp, float* __restrict__ Cf) {
    int i = blockIdx.x * blockDim.x + threadIdx.x;
    if (i < FOUT) {
        float A = HAS_BN ? g[i] * rsqrtf(v[i] + BN_EPS) : 1.0f;
        Cf[i] = HAS_BN ? be[i] + (b[i] - m[i]) * A : b[i];
    }
    if (i < FIN_PAD * FOUT) {
        int r = i / FOUT, c = i % FOUT;
        float A = HAS_BN ? g[c] * rsqrtf(v[c] + BN_EPS) : 1.0f;
        Wp[i] = (r < fin_real) ? W[r * FOUT + c] * A : 0.0f;
    }
}

// ================= GEMM + epilogue: out = ReLU(P @ Wp + Cf) =================

template <int FIN, int FOUT>
__global__ __launch_bounds__(256) void k_gemm2(const float* __restrict__ P,
                                               const float* __restrict__ Wp,
                                               const float* __restrict__ Cf,
                                               float* __restrict__ out, int n) {
    int node = blockIdx.x * 256 + threadIdx.x;
    if (node >= n) return;

    float4 xr[FIN / 4];
    const float4* p4 = (const float4*)(P + (size_t)node * FIN);
#pragma unroll
    for (int i = 0; i < FIN / 4; ++i) xr[i] = p4[i];
    const float* x = (const float*)xr;

    float4* o4 = (float4*)(out + (size_t)node * FOUT);
#pragma unroll 1
    for (int c0 = 0; c0 < FOUT; c0 += 16) {
        float4 a0 = make_float4(0, 0, 0, 0), a1 = a0, a2 = a0, a3 = a0;
        const float* wbase = Wp + c0;
#pragma unroll
        for (int k = 0; k < FIN; ++k) {
            float xv = x[k];
            const float4* wr = (const float4*)(wbase + k * FOUT);
            float4 w0 = wr[0], w1 = wr[1], w2 = wr[2], w3 = wr[3];
            a0.x = fmaf(xv, w0.x, a0.x); a0.y = fmaf(xv, w0.y, a0.y);
            a0.z = fmaf(xv, w0.z, a0.z); a0.w = fmaf(xv, w0.w, a0.w);
            a1.x = fmaf(xv, w1.x, a1.x); a1.y = fmaf(xv, w1.y, a1.y);
            a1.z = fmaf(xv, w1.z, a1.z); a1.w = fmaf(xv, w1.w, a1.w);
            a2.x = fmaf(xv, w2.x, a2.x); a2.y = fmaf(xv, w2.y, a2.y);
            a2.z = fmaf(xv, w2.z, a2.z); a2.w = fmaf(xv, w2.w, a2.w);
            a3.x = fmaf(xv, w3.x, a3.x); a3.y = fmaf(xv, w3.y, a3.y);
            a3.z = fmaf(xv, w3.z, a3.z); a3.w = fmaf(xv, w3.w, a3.w);
        }
        const float4* c4 = (const float4*)(Cf + c0);
        float4 cA = c4[0], cB = c4[1], cC = c4[2], cD = c4[3];
        float4 r0, r1, r2, r3;
        r0.x = fmaxf(a0.x + cA.x, 0.0f); r0.y = fmaxf(a0.y + cA.y, 0.0f);
        r0.z = fmaxf(a0.z + cA.z, 0.0f); r0.w = fmaxf(a0.w + cA.w, 0.0f);
        r1.x = fmaxf(a1.x + cB.x, 0.0f); r1.y = fmaxf(a1.y + cB.y, 0.0f);
        r1.z = fmaxf(a1.z + cB.z, 0.0f); r1.w = fmaxf(a1.w + cB.w, 0.0f);
        r2.x = fmaxf(a2.x + cC.x, 0.0f); r2.y = fmaxf(a2.y + cC.y, 0.0f);
        r2.z = fmaxf(a2.z + cC.z, 0.0f); r2.w = fmaxf(a2.w + cC.w, 0.0f);
        r3.x = fmaxf(a3.x + cD.x, 0.0f); r3.y = fmaxf(a3.y + cD.y, 0.0f);
        r3.z = fmaxf(a3.z + cD.z, 0.0f); r3.w = fmaxf(a3.w + cD.w, 0.0f);
        o4[(c0 >> 2) + 0] = r0;
        o4[(c0 >> 2) + 1] = r1;
        o4[(c0 >> 2) + 2] = r2;
        o4[(c0 >> 2) + 3] = r3;
    }
}

// ================= pool =================

__global__ void k_pool(const float* __restrict__ H, const int* __restrict__ batch,
                       float* __restrict__ sums, int n) {
    int f = threadIdx.x;            // 0..127
    int base = blockIdx.x * 32;
    if (base >= n) return;
    int endn = min(base + 32, n);
    int cur = batch[base];
    float acc = 0.0f;
    for (int node = base; node < endn; ++node) {
        int bb = batch[node];
        if (bb != cur) { atomicAdd(&sums[cur * 128 + f], acc); acc = 0.0f; cur = bb; }
        acc += H[(size_t)node * 128 + f];
    }
    atomicAdd(&sums[cur * 128 + f], acc);
}

__global__ void k_cnt_bs(const int* __restrict__ batch, float* __restrict__ cnt,
                         int n, int nB) {
    int b = blockIdx.x * blockDim.x + threadIdx.x;
    if (b >= nB) return;
    int lo = 0, hi = n;
    while (lo < hi) { int mid = (lo + hi) >> 1; if (batch[mid] < b) lo = mid + 1; else hi = mid; }
    int start = lo;
    lo = 0; hi = n;
    while (lo < hi) { int mid = (lo + hi) >> 1; if (batch[mid] < b + 1) lo = mid + 1; else hi = mid; }
    cnt[b] = (float)(lo - start);
}

__global__ void k_pool_div(const float* __restrict__ sums, const float* __restrict__ cnt,
                           float* __restrict__ out, int nB) {
    int i = blockIdx.x * blockDim.x + threadIdx.x;
    if (i < nB * 128) out[i] = sums[i] / fmaxf(cnt[i >> 7], 1.0f);
}

// ================= launch =================

extern "C" void kernel_launch(void* const* d_in, const int* in_sizes, int n_in,
                              void* d_out, int out_size, void* d_ws, size_t ws_size,
                              hipStream_t stream) {
    const float* x   = (const float*)d_in[0];
    const int*   ei  = (const int*)d_in[1];
    const int*   bat = (const int*)d_in[2];
    const float* W1  = (const float*)d_in[3];
    const float* b1  = (const float*)d_in[4];
    const float* W2  = (const float*)d_in[5];
    const float* b2  = (const float*)d_in[6];
    const float* W3  = (const float*)d_in[7];
    const float* b3  = (const float*)d_in[8];
    const float* g1  = (const float*)d_in[9];
    const float* be1 = (const float*)d_in[10];
    const float* m1  = (const float*)d_in[11];
    const float* v1  = (const float*)d_in[12];
    const float* g2  = (const float*)d_in[13];
    const float* be2 = (const float*)d_in[14];
    const float* m2  = (const float*)d_in[15];
    const float* v2  = (const float*)d_in[16];

    const int N = in_sizes[0] / 22;
    const int E = in_sizes[1] / 2;
    const int B = out_size / 128;
    const int* src = ei;
    const int* dst = ei + E;

    size_t off = 0;
    char* base = (char*)d_ws;
    auto alloc = [&](size_t bytes) -> void* {
        void* p = base + off;
        off = (off + bytes + 255) & ~(size_t)255;
        return p;
    };
    int*   deg    = (int*)alloc((size_t)N * 4);
    int*   rowptr = (int*)alloc((size_t)(N + 1) * 4);
    int*   rank   = (int*)alloc((size_t)E * 4);
    int*   bsums  = (int*)alloc(512);
    float* dis    = (float*)alloc((size_t)N * 4);
    float* dinv   = (float*)alloc((size_t)N * 4);
    int2*  csr    = (int2*)alloc((size_t)E * 8);
    float* bufA   = (float*)alloc((size_t)N * 128 * 4);
    float* bufB   = (float*)alloc((size_t)N * 128 * 4);
    float* sums   = (float*)alloc((size_t)B * 128 * 4 + (size_t)B * 4);
    float* cnt    = sums + (size_t)B * 128;
    float* Wp1    = (float*)alloc(24 * 64 * 4);
    float* Wp2    = (float*)alloc(64 * 64 * 4);
    float* Wp3    = (float*)alloc(64 * 128 * 4);
    float* C1     = (float*)alloc(64 * 4);
    float* C2     = (float*)alloc(64 * 4);
    float* C3     = (float*)alloc(128 * 4);

    const int T = 256;
    auto blk = [](long long n, int t) { return (int)((n + t - 1) / t); };

    // ---- weight prep ----
    k_prep<24, 64, true ><<<blk(24 * 64, T), T, 0, stream>>>(W1, 22, b1, g1, be1, m1, v1, Wp1, C1);
    k_prep<64, 64, true ><<<blk(64 * 64, T), T, 0, stream>>>(W2, 64, b2, g2, be2, m2, v2, Wp2, C2);
    k_prep<64, 128, false><<<blk(64 * 128, T), T, 0, stream>>>(W3, 64, b3, nullptr, nullptr, nullptr, nullptr, Wp3, C3);

    // ---- CSR build (one random-atomic pass; fill is atomic-free) ----
    hipMemsetAsync(deg, 0, (size_t)N * 4, stream);
    k_hist_rank<<<blk(E, T), T, 0, stream>>>(dst, deg, rank, E);
    k_deg_fin<<<blk(N, T), T, 0, stream>>>(deg, dis, dinv, N);
    int nb = (N + SCAN_E - 1) / SCAN_E;
    k_scan_block<<<nb, SCAN_T, 0, stream>>>(deg, rowptr, bsums, N);
    k_scan_carry<<<1, 64, 0, stream>>>(bsums, nb, rowptr, N);
    k_scan_add<<<blk(N, T), T, 0, stream>>>(rowptr, bsums, N);
    k_csr_fill<<<blk(E, T), T, 0, stream>>>(src, dst, rank, dis, rowptr, csr, E);

    // ---- layer 1: agg(X) [N x 24 padded] -> gemm 24->64 (+BN folded) ----
    k_gather22<<<blk(N, 4), T, 0, stream>>>(x, rowptr, csr, dinv, bufA, N);
    k_gemm2<24, 64><<<blk(N, T), T, 0, stream>>>(bufA, Wp1, C1, bufB, N);

    // ---- layer 2: agg(h1) -> gemm 64->64 (+BN folded) ----
    k_gather64<<<blk(N, 4), T, 0, stream>>>(bufB, rowptr, csr, dinv, bufA, N);
    k_gemm2<64, 64><<<blk(N, T), T, 0, stream>>>(bufA, Wp2, C2, bufB, N);

    // ---- layer 3: agg(h2) -> gemm 64->128 ----
    k_gather64<<<blk(N, 4), T, 0, stream>>>(bufB, rowptr, csr, dinv, bufA, N);
    k_gemm2<64, 128><<<blk(N, T), T, 0, stream>>>(bufA, Wp3, C3, bufB, N);

    // ---- global mean pool ----
    hipMemsetAsync(sums, 0, (size_t)B * 128 * sizeof(float), stream);
    k_pool<<<blk(N, 32), 128, 0, stream>>>(bufB, bat, sums, N);
    k_cnt_bs<<<1, 256, 0, stream>>>(bat, cnt, N, B);
    k_pool_div<<<blk(B * 128, T), T, 0, stream>>>(sums, cnt, (float*)d_out, B);
}

// Round 8
// 479.374 us; speedup vs baseline: 13.0367x; 1.1181x over previous
//
#include <hip/hip_runtime.h>

#define BN_EPS 1e-5f

typedef _Float16 half_t;
typedef _Float16 half4 __attribute__((ext_vector_type(4)));

// ================= degree histogram + rank =================

__global__ void k_hist_rank(const int* __restrict__ dst, int* __restrict__ deg,
                            int* __restrict__ rank, int e) {
    int i = blockIdx.x * blockDim.x + threadIdx.x;
    if (i < e) rank[i] = atomicAdd(&deg[dst[i]], 1);
}

__global__ void k_deg_fin(const int* __restrict__ deg, float* __restrict__ dis,
                          float* __restrict__ dinv, int n) {
    int i = blockIdx.x * blockDim.x + threadIdx.x;
    if (i < n) {
        float d = (float)(deg[i] + 1);   // + self-loop
        dis[i]  = rsqrtf(d);
        dinv[i] = 1.0f / d;
    }
}

// ================= exclusive scan (rowptr) =================

#define SCAN_T 256
#define SCAN_E 1024

__global__ void k_scan_block(const int* __restrict__ in, int* __restrict__ out,
                             int* __restrict__ bsums, int n) {
    __shared__ int lds[SCAN_T];
    int t = threadIdx.x;
    int base = blockIdx.x * SCAN_E + t * 4;
    int v[4];
#pragma unroll
    for (int j = 0; j < 4; ++j) { int idx = base + j; v[j] = (idx < n) ? in[idx] : 0; }
    int s0 = v[0] + v[1] + v[2] + v[3];
    int val = s0;
    lds[t] = val;
    __syncthreads();
    for (int off = 1; off < SCAN_T; off <<= 1) {
        int tmp = (t >= off) ? lds[t - off] : 0;
        __syncthreads();
        val += tmp;
        lds[t] = val;
        __syncthreads();
    }
    int run = val - s0;
#pragma unroll
    for (int j = 0; j < 4; ++j) { int idx = base + j; if (idx < n) out[idx] = run; run += v[j]; }
    if (t == SCAN_T - 1) bsums[blockIdx.x] = val;
}

__global__ void k_scan_carry(int* __restrict__ bsums, int nb, int* __restrict__ rowptr, int n) {
    if (threadIdx.x == 0 && blockIdx.x == 0) {
        int run = 0;
        for (int i = 0; i < nb; ++i) { int t = bsums[i]; bsums[i] = run; run += t; }
        rowptr[n] = run;
    }
}

__global__ void k_scan_add(int* __restrict__ out, const int* __restrict__ bsums, int n) {
    int i = blockIdx.x * blockDim.x + threadIdx.x;
    if (i < n) out[i] += bsums[i / SCAN_E];
}

// ================= CSR fill — atomic-free scatter using rank =================

__global__ void k_csr_fill(const int* __restrict__ src, const int* __restrict__ dst,
                           const int* __restrict__ rank, const float* __restrict__ dis,
                           const int* __restrict__ rowptr, int2* __restrict__ csr, int e) {
    int i = blockIdx.x * blockDim.x + threadIdx.x;
    if (i >= e) return;
    int s = src[i], d = dst[i];
    int p = rowptr[d] + rank[i];
    csr[p] = make_int2(s, __float_as_int(dis[s] * dis[d]));
}

// ================= X -> fp16 padded 24-wide =================

__global__ void k_x2h(const float* __restrict__ X, half_t* __restrict__ Xh, int n) {
    int i = blockIdx.x * blockDim.x + threadIdx.x;
    if (i >= n * 24) return;
    int node = i / 24, c = i % 24;
    Xh[i] = (c < 22) ? (half_t)X[(size_t)node * 22 + c] : (half_t)0.0f;
}

// ================= gather-aggregate (fp16 features, fp32 accumulate) =================
// 24-wide: wave = node; lane = esub(8) x sub(8); sub 0..5 active, half4 (8B) loads;
// 16 edges in flight (2 chains of 8 edges/instr)

__global__ void k_gather22h(const half_t* __restrict__ Xh, const int* __restrict__ rowptr,
                            const int2* __restrict__ csr, const float* __restrict__ dinv,
                            float* __restrict__ out, int n) {
    int node = blockIdx.x * 4 + (threadIdx.x >> 6);
    if (node >= n) return;
    int lane = threadIdx.x & 63;
    int esub = lane >> 3;        // 0..7
    int sub  = lane & 7;         // 0..7
    bool act = sub < 6;
    const half4* X4 = (const half4*)Xh;   // 6 half4 per node
    int beg = rowptr[node], end = rowptr[node + 1];
    float4 a0 = make_float4(0, 0, 0, 0), a1 = a0;
    for (int e = beg; e < end; e += 16) {
        int i0 = e + esub, i1 = e + 8 + esub;
        int2 m0 = csr[min(i0, end - 1)];
        int2 m1 = csr[min(i1, end - 1)];
        if (act && i0 < end) {
            float nn = __int_as_float(m0.y);
            half4 h = X4[(size_t)m0.x * 6 + sub];
            a0.x = fmaf((float)h.x, nn, a0.x); a0.y = fmaf((float)h.y, nn, a0.y);
            a0.z = fmaf((float)h.z, nn, a0.z); a0.w = fmaf((float)h.w, nn, a0.w);
        }
        if (act && i1 < end) {
            float nn = __int_as_float(m1.y);
            half4 h = X4[(size_t)m1.x * 6 + sub];
            a1.x = fmaf((float)h.x, nn, a1.x); a1.y = fmaf((float)h.y, nn, a1.y);
            a1.z = fmaf((float)h.z, nn, a1.z); a1.w = fmaf((float)h.w, nn, a1.w);
        }
    }
    float4 acc;
    acc.x = a0.x + a1.x; acc.y = a0.y + a1.y; acc.z = a0.z + a1.z; acc.w = a0.w + a1.w;
#pragma unroll
    for (int d = 8; d <= 32; d <<= 1) {
        acc.x += __shfl_xor(acc.x, d); acc.y += __shfl_xor(acc.y, d);
        acc.z += __shfl_xor(acc.z, d); acc.w += __shfl_xor(acc.w, d);
    }
    if (esub == 0 && act) {
        float di = dinv[node];
        half4 hs = X4[(size_t)node * 6 + sub];
        float4 r;
        r.x = fmaf((float)hs.x, di, acc.x);
        r.y = fmaf((float)hs.y, di, acc.y);
        r.z = fmaf((float)hs.z, di, acc.z);
        r.w = fmaf((float)hs.w, di, acc.w);
        ((float4*)out)[(size_t)node * 6 + sub] = r;
    }
}

// 64-wide fp16: wave = node; lane = esub(4) x sub(16); half4 (8B) loads;
// 16 edges in flight (4 chains of 4 edges/instr)
__global__ void k_gather64h(const half_t* __restrict__ H, const int* __restrict__ rowptr,
                            const int2* __restrict__ csr, const float* __restrict__ dinv,
                            float* __restrict__ out, int n) {
    int node = blockIdx.x * 4 + (threadIdx.x >> 6);
    if (node >= n) return;
    int lane = threadIdx.x & 63;
    int esub = lane >> 4;        // 0..3
    int sub  = lane & 15;        // 0..15
    const half4* H4 = (const half4*)H;    // 16 half4 per node
    int beg = rowptr[node], end = rowptr[node + 1];
    float4 a0 = make_float4(0, 0, 0, 0), a1 = a0, a2 = a0, a3 = a0;
    for (int e = beg; e < end; e += 16) {
        int i0 = e + esub, i1 = e + 4 + esub, i2 = e + 8 + esub, i3 = e + 12 + esub;
        int2 m0 = csr[min(i0, end - 1)];
        int2 m1 = csr[min(i1, end - 1)];
        int2 m2 = csr[min(i2, end - 1)];
        int2 m3 = csr[min(i3, end - 1)];
        if (i0 < end) {
            float nn = __int_as_float(m0.y);
            half4 h = H4[(size_t)m0.x * 16 + sub];
            a0.x = fmaf((float)h.x, nn, a0.x); a0.y = fmaf((float)h.y, nn, a0.y);
            a0.z = fmaf((float)h.z, nn, a0.z); a0.w = fmaf((float)h.w, nn, a0.w);
        }
        if (i1 < end) {
            float nn = __int_as_float(m1.y);
            half4 h = H4[(size_t)m1.x * 16 + sub];
            a1.x = fmaf((float)h.x, nn, a1.x); a1.y = fmaf((float)h.y, nn, a1.y);
            a1.z = fmaf((float)h.z, nn, a1.z); a1.w = fmaf((float)h.w, nn, a1.w);
        }
        if (i2 < end) {
            float nn = __int_as_float(m2.y);
            half4 h = H4[(size_t)m2.x * 16 + sub];
            a2.x = fmaf((float)h.x, nn, a2.x); a2.y = fmaf((float)h.y, nn, a2.y);
            a2.z = fmaf((float)h.z, nn, a2.z); a2.w = fmaf((float)h.w, nn, a2.w);
        }
        if (i3 < end) {
            float nn = __int_as_float(m3.y);
            half4 h = H4[(size_t)m3.x * 16 + sub];
            a3.x = fmaf((float)h.x, nn, a3.x); a3.y = fmaf((float)h.y, nn, a3.y);
            a3.z = fmaf((float)h.z, nn, a3.z); a3.w = fmaf((float)h.w, nn, a3.w);
        }
    }
    float4 acc;
    acc.x = (a0.x + a1.x) + (a2.x + a3.x);
    acc.y = (a0.y + a1.y) + (a2.y + a3.y);
    acc.z = (a0.z + a1.z) + (a2.z + a3.z);
    acc.w = (a0.w + a1.w) + (a2.w + a3.w);
#pragma unroll
    for (int d = 16; d <= 32; d <<= 1) {
        acc.x += __shfl_xor(acc.x, d); acc.y += __shfl_xor(acc.y, d);
        acc.z += __shfl_xor(acc.z, d); acc.w += __shfl_xor(acc.w, d);
    }
    if (esub == 0) {
        float di = dinv[node];
        half4 hs = H4[(size_t)node * 16 + sub];
        float4 r;
        r.x = fmaf((float)hs.x, di, acc.x);
        r.y = fmaf((float)hs.y, di, acc.y);
        r.z = fmaf((float)hs.z, di, acc.z);
        r.w = fmaf((float)hs.w, di, acc.w);
        ((float4*)out)[(size_t)node * 16 + sub] = r;
    }
}

// ================= weight prep =================

template <int FIN_PAD, int FOUT, bool HAS_BN>
__global__ void k_prep(const float* __restrict__ W, int fin_real,
                       const float* __restrict__ b, const float* __restrict__ g,
                       const float* __restrict__ be, const float* __restrict__ m,
                       const float* __restrict__ v,
                       float* __restrict__ Wp, float* __restrict__ Cf) {
    int i = blockIdx.x * blockDim.x + threadIdx.x;
    if (i < FOUT) {
        float A = HAS_BN ? g[i] * rsqrtf(v[i] + BN_EPS) : 1.0f;
        Cf[i] = HAS_BN ? be[i] + (b[i] - m[i]) * A : b[i];
    }
    if (i < FIN_PAD * FOUT) {
        int r = i / FOUT, c = i % FOUT;
        float A = HAS_BN ? g[c] * rsqrtf(v[c] + BN_EPS) : 1.0f;
        Wp[i] = (r < fin_real) ? W[r * FOUT + c] * A : 0.0f;
    }
}

// ================= GEMM + epilogue: out = ReLU(P @ Wp + Cf) =================
// OUT_HALF: write fp16 (for gather input); else fp32.

template <int FIN, int FOUT, bool OUT_HALF>
__global__ __launch_bounds__(256) void k_gemm2(const float* __restrict__ P,
                                               const float* __restrict__ Wp,
                                               const float* __restrict__ Cf,
                                               void* __restrict__ outp, int n) {
    int node = blockIdx.x * 256 + threadIdx.x;
    if (node >= n) return;

    float4 xr[FIN / 4];
    const float4* p4 = (const float4*)(P + (size_t)node * FIN);
#pragma unroll
    for (int i = 0; i < FIN / 4; ++i) xr[i] = p4[i];
    const float* x = (const float*)xr;

#pragma unroll 1
    for (int c0 = 0; c0 < FOUT; c0 += 16) {
        float4 a0 = make_float4(0, 0, 0, 0), a1 = a0, a2 = a0, a3 = a0;
        const float* wbase = Wp + c0;
#pragma unroll
        for (int k = 0; k < FIN; ++k) {
            float xv = x[k];
            const float4* wr = (const float4*)(wbase + k * FOUT);
            float4 w0 = wr[0], w1 = wr[1], w2 = wr[2], w3 = wr[3];
            a0.x = fmaf(xv, w0.x, a0.x); a0.y = fmaf(xv, w0.y, a0.y);
            a0.z = fmaf(xv, w0.z, a0.z); a0.w = fmaf(xv, w0.w, a0.w);
            a1.x = fmaf(xv, w1.x, a1.x); a1.y = fmaf(xv, w1.y, a1.y);
            a1.z = fmaf(xv, w1.z, a1.z); a1.w = fmaf(xv, w1.w, a1.w);
            a2.x = fmaf(xv, w2.x, a2.x); a2.y = fmaf(xv, w2.y, a2.y);
            a2.z = fmaf(xv, w2.z, a2.z); a2.w = fmaf(xv, w2.w, a2.w);
            a3.x = fmaf(xv, w3.x, a3.x); a3.y = fmaf(xv, w3.y, a3.y);
            a3.z = fmaf(xv, w3.z, a3.z); a3.w = fmaf(xv, w3.w, a3.w);
        }
        const float4* c4 = (const float4*)(Cf + c0);
        float4 cA = c4[0], cB = c4[1], cC = c4[2], cD = c4[3];
        float4 r0, r1, r2, r3;
        r0.x = fmaxf(a0.x + cA.x, 0.0f); r0.y = fmaxf(a0.y + cA.y, 0.0f);
        r0.z = fmaxf(a0.z + cA.z, 0.0f); r0.w = fmaxf(a0.w + cA.w, 0.0f);
        r1.x = fmaxf(a1.x + cB.x, 0.0f); r1.y = fmaxf(a1.y + cB.y, 0.0f);
        r1.z = fmaxf(a1.z + cB.z, 0.0f); r1.w = fmaxf(a1.w + cB.w, 0.0f);
        r2.x = fmaxf(a2.x + cC.x, 0.0f); r2.y = fmaxf(a2.y + cC.y, 0.0f);
        r2.z = fmaxf(a2.z + cC.z, 0.0f); r2.w = fmaxf(a2.w + cC.w, 0.0f);
        r3.x = fmaxf(a3.x + cD.x, 0.0f); r3.y = fmaxf(a3.y + cD.y, 0.0f);
        r3.z = fmaxf(a3.z + cD.z, 0.0f); r3.w = fmaxf(a3.w + cD.w, 0.0f);
        if (OUT_HALF) {
            half4* oh = (half4*)((half_t*)outp + (size_t)node * FOUT);
            half4 h0, h1h, h2h, h3h;
            h0.x = (half_t)r0.x; h0.y = (half_t)r0.y; h0.z = (half_t)r0.z; h0.w = (half_t)r0.w;
            h1h.x = (half_t)r1.x; h1h.y = (half_t)r1.y; h1h.z = (half_t)r1.z; h1h.w = (half_t)r1.w;
            h2h.x = (half_t)r2.x; h2h.y = (half_t)r2.y; h2h.z = (half_t)r2.z; h2h.w = (half_t)r2.w;
            h3h.x = (half_t)r3.x; h3h.y = (half_t)r3.y; h3h.z = (half_t)r3.z; h3h.w = (half_t)r3.w;
            oh[(c0 >> 2) + 0] = h0;
            oh[(c0 >> 2) + 1] = h1h;
            oh[(c0 >> 2) + 2] = h2h;
            oh[(c0 >> 2) + 3] = h3h;
        } else {
            float4* o4 = (float4*)((float*)outp + (size_t)node * FOUT);
            o4[(c0 >> 2) + 0] = r0;
            o4[(c0 >> 2) + 1] = r1;
            o4[(c0 >> 2) + 2] = r2;
            o4[(c0 >> 2) + 3] = r3;
        }
    }
}

// ================= pool =================

__global__ void k_pool(const float* __restrict__ H, const int* __restrict__ batch,
                       float* __restrict__ sums, int n) {
    int f = threadIdx.x;            // 0..127
    int base = blockIdx.x * 32;
    if (base >= n) return;
    int endn = min(base + 32, n);
    int cur = batch[base];
    float acc = 0.0f;
    for (int node = base; node < endn; ++node) {
        int bb = batch[node];
        if (bb != cur) { atomicAdd(&sums[cur * 128 + f], acc); acc = 0.0f; cur = bb; }
        acc += H[(size_t)node * 128 + f];
    }
    atomicAdd(&sums[cur * 128 + f], acc);
}

__global__ void k_cnt_bs(const int* __restrict__ batch, float* __restrict__ cnt,
                         int n, int nB) {
    int b = blockIdx.x * blockDim.x + threadIdx.x;
    if (b >= nB) return;
    int lo = 0, hi = n;
    while (lo < hi) { int mid = (lo + hi) >> 1; if (batch[mid] < b) lo = mid + 1; else hi = mid; }
    int start = lo;
    lo = 0; hi = n;
    while (lo < hi) { int mid = (lo + hi) >> 1; if (batch[mid] < b + 1) lo = mid + 1; else hi = mid; }
    cnt[b] = (float)(lo - start);
}

__global__ void k_pool_div(const float* __restrict__ sums, const float* __restrict__ cnt,
                           float* __restrict__ out, int nB) {
    int i = blockIdx.x * blockDim.x + threadIdx.x;
    if (i < nB * 128) out[i] = sums[i] / fmaxf(cnt[i >> 7], 1.0f);
}

// ================= launch =================

extern "C" void kernel_launch(void* const* d_in, const int* in_sizes, int n_in,
                              void* d_out, int out_size, void* d_ws, size_t ws_size,
                              hipStream_t stream) {
    const float* x   = (const float*)d_in[0];
    const int*   ei  = (const int*)d_in[1];
    const int*   bat = (const int*)d_in[2];
    const float* W1  = (const float*)d_in[3];
    const float* b1  = (const float*)d_in[4];
    const float* W2  = (const float*)d_in[5];
    const float* b2  = (const float*)d_in[6];
    const float* W3  = (const float*)d_in[7];
    const float* b3  = (const float*)d_in[8];
    const float* g1  = (const float*)d_in[9];
    const float* be1 = (const float*)d_in[10];
    const float* m1  = (const float*)d_in[11];
    const float* v1  = (const float*)d_in[12];
    const float* g2  = (const float*)d_in[13];
    const float* be2 = (const float*)d_in[14];
    const float* m2  = (const float*)d_in[15];
    const float* v2  = (const float*)d_in[16];

    const int N = in_sizes[0] / 22;
    const int E = in_sizes[1] / 2;
    const int B = out_size / 128;
    const int* src = ei;
    const int* dst = ei + E;

    size_t off = 0;
    char* base = (char*)d_ws;
    auto alloc = [&](size_t bytes) -> void* {
        void* p = base + off;
        off = (off + bytes + 255) & ~(size_t)255;
        return p;
    };
    int*    deg    = (int*)alloc((size_t)N * 4);
    int*    rowptr = (int*)alloc((size_t)(N + 1) * 4);
    int*    rank   = (int*)alloc((size_t)E * 4);
    int*    bsums  = (int*)alloc(512);
    float*  dis    = (float*)alloc((size_t)N * 4);
    float*  dinv   = (float*)alloc((size_t)N * 4);
    int2*   csr    = (int2*)alloc((size_t)E * 8);
    half_t* Xh     = (half_t*)alloc((size_t)N * 24 * 2);
    half_t* Hh     = (half_t*)alloc((size_t)N * 64 * 2);   // fp16 h1 / h2
    float*  bufA   = (float*)alloc((size_t)N * 128 * 4);   // fp32 agg / h3
    float*  bufB   = (float*)alloc((size_t)N * 128 * 4);
    float*  sums   = (float*)alloc((size_t)B * 128 * 4 + (size_t)B * 4);
    float*  cnt    = sums + (size_t)B * 128;
    float*  Wp1    = (float*)alloc(24 * 64 * 4);
    float*  Wp2    = (float*)alloc(64 * 64 * 4);
    float*  Wp3    = (float*)alloc(64 * 128 * 4);
    float*  C1     = (float*)alloc(64 * 4);
    float*  C2     = (float*)alloc(64 * 4);
    float*  C3     = (float*)alloc(128 * 4);

    const int T = 256;
    auto blk = [](long long n, int t) { return (int)((n + t - 1) / t); };

    // ---- weight prep ----
    k_prep<24, 64, true ><<<blk(24 * 64, T), T, 0, stream>>>(W1, 22, b1, g1, be1, m1, v1, Wp1, C1);
    k_prep<64, 64, true ><<<blk(64 * 64, T), T, 0, stream>>>(W2, 64, b2, g2, be2, m2, v2, Wp2, C2);
    k_prep<64, 128, false><<<blk(64 * 128, T), T, 0, stream>>>(W3, 64, b3, nullptr, nullptr, nullptr, nullptr, Wp3, C3);

    // ---- CSR build ----
    hipMemsetAsync(deg, 0, (size_t)N * 4, stream);
    k_hist_rank<<<blk(E, T), T, 0, stream>>>(dst, deg, rank, E);
    k_deg_fin<<<blk(N, T), T, 0, stream>>>(deg, dis, dinv, N);
    int nb = (N + SCAN_E - 1) / SCAN_E;
    k_scan_block<<<nb, SCAN_T, 0, stream>>>(deg, rowptr, bsums, N);
    k_scan_carry<<<1, 64, 0, stream>>>(bsums, nb, rowptr, N);
    k_scan_add<<<blk(N, T), T, 0, stream>>>(rowptr, bsums, N);
    k_csr_fill<<<blk(E, T), T, 0, stream>>>(src, dst, rank, dis, rowptr, csr, E);

    // ---- X -> fp16 (padded 24) ----
    k_x2h<<<blk((long long)N * 24, T), T, 0, stream>>>(x, Xh, N);

    // ---- layer 1: agg(Xh) -> gemm 24->64 (+BN folded), fp16 out ----
    k_gather22h<<<blk(N, 4), T, 0, stream>>>(Xh, rowptr, csr, dinv, bufA, N);
    k_gemm2<24, 64, true><<<blk(N, T), T, 0, stream>>>(bufA, Wp1, C1, Hh, N);

    // ---- layer 2: agg(h1) -> gemm 64->64 (+BN folded), fp16 out ----
    k_gather64h<<<blk(N, 4), T, 0, stream>>>(Hh, rowptr, csr, dinv, bufA, N);
    k_gemm2<64, 64, true><<<blk(N, T), T, 0, stream>>>(bufA, Wp2, C2, Hh, N);

    // ---- layer 3: agg(h2) -> gemm 64->128, fp32 out ----
    k_gather64h<<<blk(N, 4), T, 0, stream>>>(Hh, rowptr, csr, dinv, bufA, N);
    k_gemm2<64, 128, false><<<blk(N, T), T, 0, stream>>>(bufA, Wp3, C3, bufB, N);

    // ---- global mean pool ----
    hipMemsetAsync(sums, 0, (size_t)B * 128 * sizeof(float), stream);
    k_pool<<<blk(N, 32), 128, 0, stream>>>(bufB, bat, sums, N);
    k_cnt_bs<<<1, 256, 0, stream>>>(bat, cnt, N, B);
    k_pool_div<<<blk(B * 128, T), T, 0, stream>>>(sums, cnt, (float*)d_out, B);
}